// Round 11
// baseline (805.231 us; speedup 1.0000x reference)
//
#include <hip/hip_runtime.h>
#include <hip/hip_bf16.h>
#include <cstdint>
#include <cstddef>

#define NNODES 100000
#define NEDGES 1600000
#define EPLUS  (NEDGES + NNODES)   // edges + self loops
#define NHEADS 4
#define NB     ((NNODES + 255) / 256)   // 391 scan blocks

typedef __hip_bfloat16 bf16;
typedef unsigned short u16;
typedef __attribute__((ext_vector_type(8))) short bf16x8;
typedef __attribute__((ext_vector_type(4))) float f32x4;

// flag indices
#define F_X    0
#define F_WL1  1
#define F_BL1  2
#define F_WR1  3
#define F_BR1  4
#define F_ATT1 5
#define F_BO1  6
#define F_WL2  7
#define F_BL2  8
#define F_WR2  9
#define F_BR2  10
#define F_ATT2 11
#define F_BO2  12
#define F_EI64 13

__device__ __forceinline__ float u2f(u16 s) { return __uint_as_float(((unsigned)s) << 16); }
__device__ __forceinline__ u16  f2u(float f) {
    return __bfloat16_as_ushort(__float2bfloat16(f));
}
__device__ __forceinline__ float ld_any(const void* p, long i, int f32) {
    return f32 ? ((const float*)p)[i] : u2f(((const u16*)p)[i]);
}

// ---- dtype detection for every float tensor + edge_index width ------------
__global__ void detect_all(const u16* x, const u16* Wl1, const u16* bl1,
                           const u16* Wr1, const u16* br1, const u16* att1,
                           const u16* bo1, const u16* Wl2, const u16* bl2,
                           const u16* Wr2, const u16* br2, const u16* att2,
                           const u16* bo2, const int* ei, int* flags) {
    const int t = threadIdx.x;
    const u16* ptrs[13] = {x, Wl1, bl1, Wr1, br1, att1, bo1,
                           Wl2, bl2, Wr2, br2, att2, bo2};
    const int cnts[13] = {NNODES * 64, 64 * 64, 64, 64 * 64, 64, 64, 64,
                          64 * 256, 256, 64 * 256, 256, 256, 64};
    if (t < 13) {
        const u16* p = ptrs[t];
        const int cnt = cnts[t];
        int weird = 0, n = 0;
        for (int k = 0; k < 128; ++k) {
            int idx = 2 * k;
            if (idx >= cnt) break;
            u16 v = p[idx];
            n++;
            int ex = (v >> 7) & 0xFF;
            if (v != 0 && (ex < 96 || ex > 143)) weird++;
        }
        flags[t] = (weird * 4 > n) ? 1 : 0;   // 1 => f32
    } else if (t == 13) {
        int any = 0;
        for (int k = 0; k < 64; ++k) any |= ei[2 * k + 1];
        flags[F_EI64] = (any == 0) ? 1 : 0;   // 1 => int64
    }
}

__device__ __forceinline__ void edge_sd(const int* __restrict__ ei, int i64,
                                        int e, int& s, int& d) {
    if (e >= NEDGES) { s = d = e - NEDGES; return; }   // self loop
    if (i64) {
        const long long* p = (const long long*)ei;
        s = (int)p[e]; d = (int)p[NEDGES + e];
    } else {
        s = ei[e]; d = ei[NEDGES + e];
    }
    s = min(max(s, 0), NNODES - 1);
    d = min(max(d, 0), NNODES - 1);
}

// ---- mega conv kernel: xc convert + 4 weight transposes + biases + hist ---
#define XB 6250            // xc blocks (4 elems/thread)
#define WB 160             // weight blocks (40960 elems)
#define BB 3               // bias blocks
#define HB 6250            // hist blocks
__global__ __launch_bounds__(256)
void conv_all(const void* __restrict__ x,
              const void* __restrict__ Wl1, const void* __restrict__ Wr1,
              const void* __restrict__ Wl2, const void* __restrict__ Wr2,
              const void* __restrict__ bl1, const void* __restrict__ br1,
              const void* __restrict__ bl2, const void* __restrict__ br2,
              const int* __restrict__ ei, const int* __restrict__ flags,
              u16* __restrict__ xc, u16* __restrict__ wt1l, u16* __restrict__ wt1r,
              u16* __restrict__ wt2l, u16* __restrict__ wt2r,
              u16* __restrict__ bcs, int* __restrict__ cnt) {
    int b = blockIdx.x;
    if (b < XB) {                       // ---- xc: bf16 canonical copy of x
        const long i4 = ((long)b * 256 + threadIdx.x) * 4;
        if (i4 < (long)NNODES * 64) {
            if (flags[F_X]) {
                const float4 v = *(const float4*)((const float*)x + i4);
                ushort4 o; o.x=f2u(v.x); o.y=f2u(v.y); o.z=f2u(v.z); o.w=f2u(v.w);
                *(ushort4*)(xc + i4) = o;
            } else {
                *(ushort4*)(xc + i4) = *(const ushort4*)((const u16*)x + i4);
            }
        }
        return;
    }
    b -= XB;
    if (b < WB) {                       // ---- weight transposes W[64][M]->Wt[M][64]
        const int e = b * 256 + threadIdx.x;
        const void* W; u16* wt; int M, fwi, local;
        if (e < 4096)        { W = Wl1; wt = wt1l; M = 64;  fwi = F_WL1; local = e; }
        else if (e < 8192)   { W = Wr1; wt = wt1r; M = 64;  fwi = F_WR1; local = e - 4096; }
        else if (e < 24576)  { W = Wl2; wt = wt2l; M = 256; fwi = F_WL2; local = e - 8192; }
        else                 { W = Wr2; wt = wt2r; M = 256; fwi = F_WR2; local = e - 24576; }
        const int m = local >> 6, k = local & 63;
        wt[local] = f2u(ld_any(W, (long)k * M + m, flags[fwi]));
        return;
    }
    b -= WB;
    if (b < BB) {                       // ---- biases into bcs[640]
        const int t = b * 256 + threadIdx.x;
        if (t < 64)       bcs[t] = f2u(ld_any(bl1, t,       flags[F_BL1]));
        else if (t < 128) bcs[t] = f2u(ld_any(br1, t - 64,  flags[F_BR1]));
        else if (t < 384) bcs[t] = f2u(ld_any(bl2, t - 128, flags[F_BL2]));
        else if (t < 640) bcs[t] = f2u(ld_any(br2, t - 384, flags[F_BR2]));
        return;
    }
    b -= BB;
    {                                   // ---- dst histogram
        const int e = b * 256 + threadIdx.x;
        if (e >= NEDGES) return;
        int d;
        if (flags[F_EI64]) d = (int)((const long long*)ei)[NEDGES + e];
        else               d = ei[NEDGES + e];
        d = min(max(d, 0), NNODES - 1);
        atomicAdd(&cnt[d], 1);
    }
}

// ---------------- CSR scan / fill ------------------------------------------
__global__ __launch_bounds__(256)
void scan1_kernel(const int* __restrict__ cnt, int* __restrict__ tmp,
                  int* __restrict__ bsum) {
    __shared__ int sh[256];
    const int idx = blockIdx.x * 256 + threadIdx.x;
    int v = (idx < NNODES) ? cnt[idx] + 1 : 0;
    sh[threadIdx.x] = v;
    __syncthreads();
    for (int off = 1; off < 256; off <<= 1) {
        int t = (threadIdx.x >= off) ? sh[threadIdx.x - off] : 0;
        __syncthreads();
        sh[threadIdx.x] += t;
        __syncthreads();
    }
    if (idx < NNODES) tmp[idx] = sh[threadIdx.x];
    if (threadIdx.x == 255) bsum[blockIdx.x] = sh[255];
}

__global__ __launch_bounds__(512)
void scan2_kernel(int* __restrict__ bsum) {
    __shared__ int sh[512];
    const int t = threadIdx.x;
    sh[t] = (t < NB) ? bsum[t] : 0;
    __syncthreads();
    for (int off = 1; off < 512; off <<= 1) {
        int v = (t >= off) ? sh[t - off] : 0;
        __syncthreads();
        sh[t] += v;
        __syncthreads();
    }
    if (t < NB) bsum[t] = sh[t];
}

__global__ __launch_bounds__(256)
void scan3_kernel(const int* __restrict__ tmp, const int* __restrict__ bsum,
                  int* __restrict__ row_ptr) {
    const int idx = blockIdx.x * 256 + threadIdx.x;
    if (idx < NNODES) {
        int off = (blockIdx.x > 0) ? bsum[blockIdx.x - 1] : 0;
        row_ptr[idx + 1] = tmp[idx] + off;
    }
    if (idx == 0) row_ptr[0] = 0;
}

__global__ __launch_bounds__(256)
void fill_kernel(const int* __restrict__ ei, const int* __restrict__ flags,
                 const int* __restrict__ row_ptr, int* __restrict__ cur,
                 int* __restrict__ csr_src) {
    const int e = blockIdx.x * 256 + threadIdx.x;
    if (e >= EPLUS) return;
    int s, d;
    edge_sd(ei, flags[F_EI64], e, s, d);
    int slot = row_ptr[d] + atomicAdd(&cur[d], 1);
    csr_src[slot] = s;
}

// ---------------- MFMA GEMM: out[N,M] = xc[N,64] @ W + b, bf16 out ---------
template<int M, int RPB>
__global__ __launch_bounds__(256)
void gemm_mfma(const u16* __restrict__ xc, const u16* __restrict__ wt,
               const u16* __restrict__ bc, u16* __restrict__ out) {
    constexpr int MT = RPB / 16;
    constexpr int NT = M / 64;
    const int wave = threadIdx.x >> 6;
    const int lane = threadIdx.x & 63;
    const int quad = lane >> 4;
    const int l16  = lane & 15;
    const int row0 = blockIdx.x * RPB;
    const int col0 = wave * (M / 4);

    bf16x8 bfrag[NT][2];
#pragma unroll
    for (int nt = 0; nt < NT; ++nt)
#pragma unroll
        for (int c = 0; c < 2; ++c)
            bfrag[nt][c] = *(const bf16x8*)(wt +
                ((size_t)(col0 + nt * 16 + l16) * 64 + c * 32 + quad * 8));

    f32x4 acc[MT][NT];
#pragma unroll
    for (int mt = 0; mt < MT; ++mt)
#pragma unroll
        for (int nt = 0; nt < NT; ++nt)
            acc[mt][nt] = f32x4{0.f, 0.f, 0.f, 0.f};

#pragma unroll
    for (int mt = 0; mt < MT; ++mt) {
        int row = row0 + mt * 16 + l16;
        row = (row < NNODES) ? row : (NNODES - 1);
#pragma unroll
        for (int c = 0; c < 2; ++c) {
            bf16x8 afrag = *(const bf16x8*)(xc + ((size_t)row * 64 + c * 32 + quad * 8));
#pragma unroll
            for (int nt = 0; nt < NT; ++nt)
                acc[mt][nt] = __builtin_amdgcn_mfma_f32_16x16x32_bf16(
                    afrag, bfrag[nt][c], acc[mt][nt], 0, 0, 0);
        }
    }

#pragma unroll
    for (int mt = 0; mt < MT; ++mt) {
#pragma unroll
        for (int nt = 0; nt < NT; ++nt) {
            const int col = col0 + nt * 16 + l16;
            const float bias = u2f(bc[col]);
#pragma unroll
            for (int r = 0; r < 4; ++r) {
                const int row = row0 + mt * 16 + quad * 4 + r;
                if (row < NNODES)
                    out[(size_t)row * M + col] = f2u(acc[mt][nt][r] + bias);
            }
        }
    }
}

// ---------------- fused per-destination GATv2 ------------------------------
// ONE dst per 256-thread block; its edge list is strided across the 4 waves
// (wave w takes edges beg+w, beg+w+4, ...). Per iteration a wave handles one
// edge with the R9-proven layout: 64 lanes x VEC channels, ushort4/u16 loads,
// head = lane>>4, 4-shuffle head reduce, online denom+acc in registers.
// Partials combine through LDS once per dst. No f32 global atomics.
template<int HC, bool MEAN, typename TO>
__global__ __launch_bounds__(256)
void fused_gat(const u16* __restrict__ xl, const u16* __restrict__ xr,
               const int* __restrict__ row_ptr, const int* __restrict__ csr_src,
               const void* __restrict__ att, const void* __restrict__ bo,
               const int* __restrict__ flags, int fai, int fbi,
               TO* __restrict__ out) {
    constexpr int VEC = HC / 64;
    __shared__ float sh_acc[4][64][VEC];
    __shared__ float sh_den[4][64];
    const int d    = blockIdx.x;
    const int wave = threadIdx.x >> 6;
    const int lane = threadIdx.x & 63;
    const int fatt = flags[fai];

    float attv[VEC], rv[VEC];
#pragma unroll
    for (int j = 0; j < VEC; ++j)
        attv[j] = ld_any(att, lane * VEC + j, fatt);
    if constexpr (VEC == 4) {
        ushort4 r = *(const ushort4*)(xr + (size_t)d * HC + lane * 4);
        rv[0]=u2f(r.x); rv[1]=u2f(r.y); rv[2]=u2f(r.z); rv[3]=u2f(r.w);
    } else {
        rv[0] = u2f(xr[(size_t)d * HC + lane]);
    }

    const int beg = row_ptr[d], end = row_ptr[d + 1];
    float denom = 0.f;
    float acc[VEC];
#pragma unroll
    for (int j = 0; j < VEC; ++j) acc[j] = 0.f;

    // this wave's first edge (may be none); prefetch with clamped index
    int i = beg + wave;
    {
        int idx = (i < end) ? i : (end - 1);
        (void)idx;
    }
    ushort4 a4; u16 a1;
    {
        int idx = (i < end) ? i : (end - 1);
        int s0 = csr_src[idx];
        if constexpr (VEC == 4)
            a4 = *(const ushort4*)(xl + (size_t)s0 * HC + lane * 4);
        else
            a1 = xl[(size_t)s0 * HC + lane];
    }

    for (; i < end; i += 4) {
        float lv[VEC];
        if constexpr (VEC == 4) {
            lv[0]=u2f(a4.x); lv[1]=u2f(a4.y); lv[2]=u2f(a4.z); lv[3]=u2f(a4.w);
        } else {
            lv[0] = u2f(a1);
        }
        if (i + 4 < end) {                       // prefetch next strided edge
            int sn = csr_src[i + 4];
            if constexpr (VEC == 4)
                a4 = *(const ushort4*)(xl + (size_t)sn * HC + lane * 4);
            else
                a1 = xl[(size_t)sn * HC + lane];
        }
        float part = 0.f;
#pragma unroll
        for (int j = 0; j < VEC; ++j) {
            float v = lv[j] + rv[j];
            v = fmaxf(v, 0.2f * v);              // leaky_relu 0.2
            part = fmaf(v, attv[j], part);
        }
#pragma unroll
        for (int off = 8; off >= 1; off >>= 1)
            part += __shfl_xor(part, off, 64);   // reduce within 16-lane head
        float ex = __expf(fminf(part, 60.f));
        denom += ex;
#pragma unroll
        for (int j = 0; j < VEC; ++j)
            acc[j] = fmaf(ex, lv[j], acc[j]);
    }

    // combine the 4 waves' partials
    sh_den[wave][lane] = denom;
#pragma unroll
    for (int j = 0; j < VEC; ++j) sh_acc[wave][lane][j] = acc[j];
    __syncthreads();
    if (wave != 0) return;

    denom = 1e-16f;
#pragma unroll
    for (int w = 0; w < 4; ++w) denom += sh_den[w][lane];
#pragma unroll
    for (int j = 0; j < VEC; ++j) {
        float a = 0.f;
#pragma unroll
        for (int w = 0; w < 4; ++w) a += sh_acc[w][lane][j];
        acc[j] = a;
    }
    const float inv = 1.f / denom;

    if constexpr (MEAN) {
#pragma unroll
        for (int j = 0; j < VEC; ++j) {
            acc[j] *= inv;
            acc[j] += __shfl_xor(acc[j], 16, 64);   // sum the 4 heads
            acc[j] += __shfl_xor(acc[j], 32, 64);
        }
        if (lane < 16) {
            const int fbo = flags[fbi];
            float4 o;
            float* op = (float*)&o;
#pragma unroll
            for (int j = 0; j < VEC; ++j) {
                float v = acc[j] * 0.25f + ld_any(bo, lane * 4 + j, fbo);
                op[j] = (v > 0.f) ? v : 0.f;
            }
            *(float4*)((float*)out + (size_t)d * 64 + lane * 4) = o;
        }
    } else {
        const int fbo = flags[fbi];
        float v = acc[0] * inv + ld_any(bo, lane, fbo);
        v = (v > 0.f) ? v : 0.f;
        ((u16*)out)[(size_t)d * 64 + lane] = f2u(v);
    }
}

__global__ void plant_kernel(float* out, float code) {
    if (code > 0.f) out[0] = code;
}

extern "C" void kernel_launch(void* const* d_in, const int* in_sizes, int n_in,
                              void* d_out, int out_size, void* d_ws, size_t ws_size,
                              hipStream_t stream) {
    // ---- host-side slot mapping by element counts ----
    int ix = -1, iei = -1;
    int i4096[2], i16384[2], i64s[5], i256[3];
    int c4 = 0, c16 = 0, c64 = 0, c256 = 0;
    bool extra = false;
    for (int i = 0; i < n_in; ++i) {
        int sz = in_sizes[i];
        if (sz == 6400000)      { if (ix < 0) ix = i; else extra = true; }
        else if (sz == 3200000) { if (iei < 0) iei = i; else extra = true; }
        else if (sz == 4096)    { if (c4  < 2) i4096[c4]  = i; c4++;  }
        else if (sz == 16384)   { if (c16 < 2) i16384[c16] = i; c16++; }
        else if (sz == 64)      { if (c64 < 5) i64s[c64]  = i; c64++; }
        else if (sz == 256)     { if (c256 < 3) i256[c256] = i; c256++; }
        else if (sz == 100000 || sz == 1) { /* frame_mask / scalar: unused */ }
        else extra = true;
    }
    bool ok = (ix >= 0) && (iei >= 0) && (c4 == 2) && (c16 == 2)
              && (c64 == 5) && (c256 == 3) && !extra;
    float code = 0.f;
    if (!ok) {
        code = 50000.f + 100.f * (float)n_in;
        ix = 0; iei = 1;
        i4096[0] = 3;  i4096[1] = 5;
        i64s[0] = 4; i64s[1] = 6; i64s[2] = 7; i64s[3] = 8; i64s[4] = 14;
        i16384[0] = 9; i16384[1] = 11;
        i256[0] = 10; i256[1] = 12; i256[2] = 13;
    }

    const u16* x    = (const u16*)d_in[ix];
    const int* ei   = (const int*)d_in[iei];
    const u16* Wl1  = (const u16*)d_in[i4096[0]];
    const u16* Wr1  = (const u16*)d_in[i4096[1]];
    const u16* bl1  = (const u16*)d_in[i64s[0]];
    const u16* br1  = (const u16*)d_in[i64s[1]];
    const u16* att1 = (const u16*)d_in[i64s[2]];
    const u16* bo1  = (const u16*)d_in[i64s[3]];
    const u16* bo2  = (const u16*)d_in[i64s[4]];
    const u16* Wl2  = (const u16*)d_in[i16384[0]];
    const u16* Wr2  = (const u16*)d_in[i16384[1]];
    const u16* bl2  = (const u16*)d_in[i256[0]];
    const u16* br2  = (const u16*)d_in[i256[1]];
    const u16* att2 = (const u16*)d_in[i256[2]];

    // ---- workspace layout (bytes), ~136.1 MB ----
    char* ws = (char*)d_ws;
    u16* xlb     = (u16*)(ws);                    // N*256 bf16 = 51.2 MB
    u16* xrb     = (u16*)(ws + 51200000);         // N*256 bf16 = 51.2 MB
    u16* hbuf    = (u16*)(ws + 102400000);        // N*64  bf16 = 12.8 MB
    u16* xc      = (u16*)(ws + 115200000);        // N*64  bf16 = 12.8 MB
    int* row_ptr = (int*)(ws + 128000000);        // (N+1)*4
    int* cnt     = (int*)(ws + 128400016);        // N*4
    int* tmp     = (int*)(ws + 128800016);        // N*4
    int* bsum    = (int*)(ws + 129200016);        // NB*4
    int* csr_src = (int*)(ws + 129201600);        // EPLUS*4 = 6.8 MB
    u16* wt1l    = (u16*)(ws + 136001600);        // 64*64 bf16
    u16* wt1r    = (u16*)(ws + 136009792);
    u16* wt2l    = (u16*)(ws + 136017984);        // 256*64 bf16
    u16* wt2r    = (u16*)(ws + 136050752);
    u16* bcs     = (u16*)(ws + 136083520);        // 640 bf16
    int* flags   = (int*)(ws + 136084800);        // 16 ints
    const size_t need = 136084864;
    if (ws_size < need) {
        float c2 = 60000.f + (float)(ws_size >> 20);
        code = (c2 > code) ? c2 : code;
    }

    const int ep_grid = (EPLUS + 255) / 256;

    detect_all<<<1, 64, 0, stream>>>(x, Wl1, bl1, Wr1, br1, att1, bo1,
                                     Wl2, bl2, Wr2, br2, att2, bo2, ei, flags);

    // ---- canonicalize + histogram (one dispatch) ----
    (void)hipMemsetAsync(cnt, 0, (size_t)NNODES * 4, stream);
    conv_all<<<XB + WB + BB + HB, 256, 0, stream>>>(
        x, Wl1, Wr1, Wl2, Wr2, bl1, br1, bl2, br2, ei, flags,
        xc, wt1l, wt1r, wt2l, wt2r, bcs, cnt);

    // ---- CSR scan + fill ----
    scan1_kernel<<<NB, 256, 0, stream>>>(cnt, tmp, bsum);
    scan2_kernel<<<1, 512, 0, stream>>>(bsum);
    scan3_kernel<<<NB, 256, 0, stream>>>(tmp, bsum, row_ptr);
    (void)hipMemsetAsync(cnt, 0, (size_t)NNODES * 4, stream);
    fill_kernel<<<ep_grid, 256, 0, stream>>>(ei, flags, row_ptr, cnt, csr_src);

    // ---- layer 1 (64 -> 4x16, concat) ----
    gemm_mfma<64, 128><<<(NNODES + 127) / 128, 256, 0, stream>>>(xc, wt1l, bcs,       xlb);
    gemm_mfma<64, 128><<<(NNODES + 127) / 128, 256, 0, stream>>>(xc, wt1r, bcs + 64,  xrb);
    fused_gat<64, false, u16><<<NNODES, 256, 0, stream>>>(
        xlb, xrb, row_ptr, csr_src, att1, bo1, flags, F_ATT1, F_BO1, hbuf);

    // ---- layer 2 (64 -> 4x64, mean) ----
    gemm_mfma<256, 64><<<(NNODES + 63) / 64, 256, 0, stream>>>(hbuf, wt2l, bcs + 128, xlb);
    gemm_mfma<256, 64><<<(NNODES + 63) / 64, 256, 0, stream>>>(hbuf, wt2r, bcs + 384, xrb);
    fused_gat<256, true, float><<<NNODES, 256, 0, stream>>>(
        xlb, xrb, row_ptr, csr_src, att2, bo2, flags, F_ATT2, F_BO2, (float*)d_out);

    plant_kernel<<<1, 1, 0, stream>>>((float*)d_out, code);
}

// Round 12
// 667.899 us; speedup vs baseline: 1.2056x; 1.2056x over previous
//
#include <hip/hip_runtime.h>
#include <hip/hip_bf16.h>
#include <cstdint>
#include <cstddef>

#define NNODES 100000
#define NEDGES 1600000
#define EPLUS  (NEDGES + NNODES)   // edges + self loops
#define NHEADS 4
#define NB     ((NNODES + 255) / 256)   // 391 scan blocks

typedef __hip_bfloat16 bf16;
typedef unsigned short u16;
typedef __attribute__((ext_vector_type(8))) short bf16x8;
typedef __attribute__((ext_vector_type(4))) float f32x4;

// flag indices
#define F_X    0
#define F_WL1  1
#define F_BL1  2
#define F_WR1  3
#define F_BR1  4
#define F_ATT1 5
#define F_BO1  6
#define F_WL2  7
#define F_BL2  8
#define F_WR2  9
#define F_BR2  10
#define F_ATT2 11
#define F_BO2  12
#define F_EI64 13

__device__ __forceinline__ float u2f(u16 s) { return __uint_as_float(((unsigned)s) << 16); }
__device__ __forceinline__ u16  f2u(float f) {
    return __bfloat16_as_ushort(__float2bfloat16(f));
}
__device__ __forceinline__ float ld_any(const void* p, long i, int f32) {
    return f32 ? ((const float*)p)[i] : u2f(((const u16*)p)[i]);
}

// ---- dtype detection for every float tensor + edge_index width ------------
__global__ void detect_all(const u16* x, const u16* Wl1, const u16* bl1,
                           const u16* Wr1, const u16* br1, const u16* att1,
                           const u16* bo1, const u16* Wl2, const u16* bl2,
                           const u16* Wr2, const u16* br2, const u16* att2,
                           const u16* bo2, const int* ei, int* flags) {
    const int t = threadIdx.x;
    const u16* ptrs[13] = {x, Wl1, bl1, Wr1, br1, att1, bo1,
                           Wl2, bl2, Wr2, br2, att2, bo2};
    const int cnts[13] = {NNODES * 64, 64 * 64, 64, 64 * 64, 64, 64, 64,
                          64 * 256, 256, 64 * 256, 256, 256, 64};
    if (t < 13) {
        const u16* p = ptrs[t];
        const int cnt = cnts[t];
        int weird = 0, n = 0;
        for (int k = 0; k < 128; ++k) {
            int idx = 2 * k;
            if (idx >= cnt) break;
            u16 v = p[idx];
            n++;
            int ex = (v >> 7) & 0xFF;
            if (v != 0 && (ex < 96 || ex > 143)) weird++;
        }
        flags[t] = (weird * 4 > n) ? 1 : 0;   // 1 => f32
    } else if (t == 13) {
        int any = 0;
        for (int k = 0; k < 64; ++k) any |= ei[2 * k + 1];
        flags[F_EI64] = (any == 0) ? 1 : 0;   // 1 => int64
    }
}

__device__ __forceinline__ void edge_sd(const int* __restrict__ ei, int i64,
                                        int e, int& s, int& d) {
    if (e >= NEDGES) { s = d = e - NEDGES; return; }   // self loop
    if (i64) {
        const long long* p = (const long long*)ei;
        s = (int)p[e]; d = (int)p[NEDGES + e];
    } else {
        s = ei[e]; d = ei[NEDGES + e];
    }
    s = min(max(s, 0), NNODES - 1);
    d = min(max(d, 0), NNODES - 1);
}

// ---- mega conv kernel: xc convert + 4 weight transposes + biases + hist ---
#define XB 6250            // xc blocks (4 elems/thread)
#define WB 160             // weight blocks (40960 elems)
#define BB 3               // bias blocks
#define HB 6250            // hist blocks
__global__ __launch_bounds__(256)
void conv_all(const void* __restrict__ x,
              const void* __restrict__ Wl1, const void* __restrict__ Wr1,
              const void* __restrict__ Wl2, const void* __restrict__ Wr2,
              const void* __restrict__ bl1, const void* __restrict__ br1,
              const void* __restrict__ bl2, const void* __restrict__ br2,
              const int* __restrict__ ei, const int* __restrict__ flags,
              u16* __restrict__ xc, u16* __restrict__ wt1l, u16* __restrict__ wt1r,
              u16* __restrict__ wt2l, u16* __restrict__ wt2r,
              u16* __restrict__ bcs, int* __restrict__ cnt) {
    int b = blockIdx.x;
    if (b < XB) {                       // ---- xc: bf16 canonical copy of x
        const long i4 = ((long)b * 256 + threadIdx.x) * 4;
        if (i4 < (long)NNODES * 64) {
            if (flags[F_X]) {
                const float4 v = *(const float4*)((const float*)x + i4);
                ushort4 o; o.x=f2u(v.x); o.y=f2u(v.y); o.z=f2u(v.z); o.w=f2u(v.w);
                *(ushort4*)(xc + i4) = o;
            } else {
                *(ushort4*)(xc + i4) = *(const ushort4*)((const u16*)x + i4);
            }
        }
        return;
    }
    b -= XB;
    if (b < WB) {                       // ---- weight transposes W[64][M]->Wt[M][64]
        const int e = b * 256 + threadIdx.x;
        const void* W; u16* wt; int M, fwi, local;
        if (e < 4096)        { W = Wl1; wt = wt1l; M = 64;  fwi = F_WL1; local = e; }
        else if (e < 8192)   { W = Wr1; wt = wt1r; M = 64;  fwi = F_WR1; local = e - 4096; }
        else if (e < 24576)  { W = Wl2; wt = wt2l; M = 256; fwi = F_WL2; local = e - 8192; }
        else                 { W = Wr2; wt = wt2r; M = 256; fwi = F_WR2; local = e - 24576; }
        const int m = local >> 6, k = local & 63;
        wt[local] = f2u(ld_any(W, (long)k * M + m, flags[fwi]));
        return;
    }
    b -= WB;
    if (b < BB) {                       // ---- biases into bcs[640]
        const int t = b * 256 + threadIdx.x;
        if (t < 64)       bcs[t] = f2u(ld_any(bl1, t,       flags[F_BL1]));
        else if (t < 128) bcs[t] = f2u(ld_any(br1, t - 64,  flags[F_BR1]));
        else if (t < 384) bcs[t] = f2u(ld_any(bl2, t - 128, flags[F_BL2]));
        else if (t < 640) bcs[t] = f2u(ld_any(br2, t - 384, flags[F_BR2]));
        return;
    }
    b -= BB;
    {                                   // ---- dst histogram
        const int e = b * 256 + threadIdx.x;
        if (e >= NEDGES) return;
        int d;
        if (flags[F_EI64]) d = (int)((const long long*)ei)[NEDGES + e];
        else               d = ei[NEDGES + e];
        d = min(max(d, 0), NNODES - 1);
        atomicAdd(&cnt[d], 1);
    }
}

// ---------------- CSR scan / fill ------------------------------------------
__global__ __launch_bounds__(256)
void scan1_kernel(const int* __restrict__ cnt, int* __restrict__ tmp,
                  int* __restrict__ bsum) {
    __shared__ int sh[256];
    const int idx = blockIdx.x * 256 + threadIdx.x;
    int v = (idx < NNODES) ? cnt[idx] + 1 : 0;
    sh[threadIdx.x] = v;
    __syncthreads();
    for (int off = 1; off < 256; off <<= 1) {
        int t = (threadIdx.x >= off) ? sh[threadIdx.x - off] : 0;
        __syncthreads();
        sh[threadIdx.x] += t;
        __syncthreads();
    }
    if (idx < NNODES) tmp[idx] = sh[threadIdx.x];
    if (threadIdx.x == 255) bsum[blockIdx.x] = sh[255];
}

__global__ __launch_bounds__(512)
void scan2_kernel(int* __restrict__ bsum) {
    __shared__ int sh[512];
    const int t = threadIdx.x;
    sh[t] = (t < NB) ? bsum[t] : 0;
    __syncthreads();
    for (int off = 1; off < 512; off <<= 1) {
        int v = (t >= off) ? sh[t - off] : 0;
        __syncthreads();
        sh[t] += v;
        __syncthreads();
    }
    if (t < NB) bsum[t] = sh[t];
}

__global__ __launch_bounds__(256)
void scan3_kernel(const int* __restrict__ tmp, const int* __restrict__ bsum,
                  int* __restrict__ row_ptr) {
    const int idx = blockIdx.x * 256 + threadIdx.x;
    if (idx < NNODES) {
        int off = (blockIdx.x > 0) ? bsum[blockIdx.x - 1] : 0;
        row_ptr[idx + 1] = tmp[idx] + off;
    }
    if (idx == 0) row_ptr[0] = 0;
}

__global__ __launch_bounds__(256)
void fill_kernel(const int* __restrict__ ei, const int* __restrict__ flags,
                 const int* __restrict__ row_ptr, int* __restrict__ cur,
                 int* __restrict__ csr_src) {
    const int e = blockIdx.x * 256 + threadIdx.x;
    if (e >= EPLUS) return;
    int s, d;
    edge_sd(ei, flags[F_EI64], e, s, d);
    int slot = row_ptr[d] + atomicAdd(&cur[d], 1);
    csr_src[slot] = s;
}

// ---------------- MFMA GEMM: both l/r transforms in one dispatch -----------
// gridDim.y = 2: y==0 -> (wtl -> outl), y==1 -> (wtr -> outr)
template<int M, int RPB>
__global__ __launch_bounds__(256)
void gemm_mfma(const u16* __restrict__ xc,
               const u16* __restrict__ wtl, const u16* __restrict__ wtr,
               const u16* __restrict__ bcl, const u16* __restrict__ bcr,
               u16* __restrict__ outl, u16* __restrict__ outr) {
    constexpr int MT = RPB / 16;
    constexpr int NT = M / 64;
    const u16* wt = blockIdx.y ? wtr : wtl;
    const u16* bc = blockIdx.y ? bcr : bcl;
    u16* out      = blockIdx.y ? outr : outl;
    const int wave = threadIdx.x >> 6;
    const int lane = threadIdx.x & 63;
    const int quad = lane >> 4;
    const int l16  = lane & 15;
    const int row0 = blockIdx.x * RPB;
    const int col0 = wave * (M / 4);

    bf16x8 bfrag[NT][2];
#pragma unroll
    for (int nt = 0; nt < NT; ++nt)
#pragma unroll
        for (int c = 0; c < 2; ++c)
            bfrag[nt][c] = *(const bf16x8*)(wt +
                ((size_t)(col0 + nt * 16 + l16) * 64 + c * 32 + quad * 8));

    f32x4 acc[MT][NT];
#pragma unroll
    for (int mt = 0; mt < MT; ++mt)
#pragma unroll
        for (int nt = 0; nt < NT; ++nt)
            acc[mt][nt] = f32x4{0.f, 0.f, 0.f, 0.f};

#pragma unroll
    for (int mt = 0; mt < MT; ++mt) {
        int row = row0 + mt * 16 + l16;
        row = (row < NNODES) ? row : (NNODES - 1);
#pragma unroll
        for (int c = 0; c < 2; ++c) {
            bf16x8 afrag = *(const bf16x8*)(xc + ((size_t)row * 64 + c * 32 + quad * 8));
#pragma unroll
            for (int nt = 0; nt < NT; ++nt)
                acc[mt][nt] = __builtin_amdgcn_mfma_f32_16x16x32_bf16(
                    afrag, bfrag[nt][c], acc[mt][nt], 0, 0, 0);
        }
    }

#pragma unroll
    for (int mt = 0; mt < MT; ++mt) {
#pragma unroll
        for (int nt = 0; nt < NT; ++nt) {
            const int col = col0 + nt * 16 + l16;
            const float bias = u2f(bc[col]);
#pragma unroll
            for (int r = 0; r < 4; ++r) {
                const int row = row0 + mt * 16 + quad * 4 + r;
                if (row < NNODES)
                    out[(size_t)row * M + col] = f2u(acc[mt][nt][r] + bias);
            }
        }
    }
}

// ------- layer-1 fused GAT: 4 edges per wave-iteration (R10-proven) --------
// wave = 4 edge slots (q=lane>>4) x 16 lanes (l); lane holds 4 channels
// (ushort4 = 8B load, 512 B per wave instruction). head = l>>2.
__global__ __launch_bounds__(256)
void gat_l1(const u16* __restrict__ xl, const u16* __restrict__ xr,
            const int* __restrict__ row_ptr, const int* __restrict__ csr_src,
            const void* __restrict__ att, const void* __restrict__ bo,
            const int* __restrict__ flags, u16* __restrict__ out) {
    const int d = blockIdx.x * 4 + (threadIdx.x >> 6);
    if (d >= NNODES) return;
    const int lane = threadIdx.x & 63;
    const int q = lane >> 4;
    const int l = lane & 15;
    const int fatt = flags[F_ATT1];

    float attv[4], rv[4];
#pragma unroll
    for (int j = 0; j < 4; ++j)
        attv[j] = ld_any(att, l * 4 + j, fatt);
    {
        ushort4 r = *(const ushort4*)(xr + (size_t)d * 64 + l * 4);
        rv[0]=u2f(r.x); rv[1]=u2f(r.y); rv[2]=u2f(r.z); rv[3]=u2f(r.w);
    }

    const int beg = row_ptr[d], end = row_ptr[d + 1];
    float denom = 1e-16f;
    float acc[4] = {0.f, 0.f, 0.f, 0.f};

    ushort4 a4;
    {
        int e0 = beg + q;
        int idx = (e0 < end) ? e0 : (end - 1);
        a4 = *(const ushort4*)(xl + (size_t)csr_src[idx] * 64 + l * 4);
    }

    for (int base = beg; base < end; base += 4) {
        float lv[4];
        lv[0]=u2f(a4.x); lv[1]=u2f(a4.y); lv[2]=u2f(a4.z); lv[3]=u2f(a4.w);
        if (base + 4 < end) {
            int en = base + 4 + q;
            int idx = (en < end) ? en : (end - 1);
            a4 = *(const ushort4*)(xl + (size_t)csr_src[idx] * 64 + l * 4);
        }
        float part = 0.f;
#pragma unroll
        for (int j = 0; j < 4; ++j) {
            float v = lv[j] + rv[j];
            v = fmaxf(v, 0.2f * v);
            part = fmaf(v, attv[j], part);
        }
        part += __shfl_xor(part, 1, 64);         // head reduce (4 lanes)
        part += __shfl_xor(part, 2, 64);
        float ex = __expf(fminf(part, 60.f));
        ex = (base + q < end) ? ex : 0.f;        // mask invalid slots
        denom += ex;
#pragma unroll
        for (int j = 0; j < 4; ++j)
            acc[j] = fmaf(ex, lv[j], acc[j]);
    }

    denom += __shfl_xor(denom, 16, 64);          // combine the 4 edge slots
    denom += __shfl_xor(denom, 32, 64);
#pragma unroll
    for (int j = 0; j < 4; ++j) {
        acc[j] += __shfl_xor(acc[j], 16, 64);
        acc[j] += __shfl_xor(acc[j], 32, 64);
    }
    const float inv = 1.f / denom;

    if (lane < 16) {                             // lanes 0-15: channels 4l..4l+3
        const int fbo = flags[F_BO1];
        ushort4 o;
        u16* op = (u16*)&o;
#pragma unroll
        for (int j = 0; j < 4; ++j) {
            float v = acc[j] * inv + ld_any(bo, l * 4 + j, fbo);
            op[j] = f2u((v > 0.f) ? v : 0.f);
        }
        *(ushort4*)(out + (size_t)d * 64 + l * 4) = o;
    }
}

// ------- layer-2 fused GAT: R9-proven wave-per-dst + 2-edge pipeline -------
// 64 lanes x 4 channels per edge (ushort4 = 8B/lane, full 512 B row/inst).
__global__ __launch_bounds__(256)
void gat_l2(const u16* __restrict__ xl, const u16* __restrict__ xr,
            const int* __restrict__ row_ptr, const int* __restrict__ csr_src,
            const void* __restrict__ att, const void* __restrict__ bo,
            const int* __restrict__ flags, float* __restrict__ out) {
    const int d = blockIdx.x * 4 + (threadIdx.x >> 6);
    if (d >= NNODES) return;
    const int lane = threadIdx.x & 63;
    const int fatt = flags[F_ATT2];

    float attv[4], rv[4];
#pragma unroll
    for (int j = 0; j < 4; ++j)
        attv[j] = ld_any(att, lane * 4 + j, fatt);
    {
        ushort4 r = *(const ushort4*)(xr + (size_t)d * 256 + lane * 4);
        rv[0]=u2f(r.x); rv[1]=u2f(r.y); rv[2]=u2f(r.z); rv[3]=u2f(r.w);
    }

    const int beg = row_ptr[d], end = row_ptr[d + 1];   // end > beg (self loop)
    float denom = 1e-16f;
    float acc[4] = {0.f, 0.f, 0.f, 0.f};

    ushort4 b0, b1;
    b0 = *(const ushort4*)(xl + (size_t)csr_src[beg] * 256 + lane * 4);
    if (beg + 1 < end)
        b1 = *(const ushort4*)(xl + (size_t)csr_src[beg + 1] * 256 + lane * 4);

    for (int i = beg; i < end; i += 2) {
        {   // edge i (b0)
            float lv[4];
            lv[0]=u2f(b0.x); lv[1]=u2f(b0.y); lv[2]=u2f(b0.z); lv[3]=u2f(b0.w);
            if (i + 2 < end)
                b0 = *(const ushort4*)(xl + (size_t)csr_src[i + 2] * 256 + lane * 4);
            float part = 0.f;
#pragma unroll
            for (int j = 0; j < 4; ++j) {
                float v = lv[j] + rv[j];
                v = fmaxf(v, 0.2f * v);
                part = fmaf(v, attv[j], part);
            }
#pragma unroll
            for (int off = 8; off >= 1; off >>= 1)
                part += __shfl_xor(part, off, 64);
            float ex = __expf(fminf(part, 60.f));
            denom += ex;
#pragma unroll
            for (int j = 0; j < 4; ++j)
                acc[j] = fmaf(ex, lv[j], acc[j]);
        }
        if (i + 1 < end) {   // edge i+1 (b1)
            float lv[4];
            lv[0]=u2f(b1.x); lv[1]=u2f(b1.y); lv[2]=u2f(b1.z); lv[3]=u2f(b1.w);
            if (i + 3 < end)
                b1 = *(const ushort4*)(xl + (size_t)csr_src[i + 3] * 256 + lane * 4);
            float part = 0.f;
#pragma unroll
            for (int j = 0; j < 4; ++j) {
                float v = lv[j] + rv[j];
                v = fmaxf(v, 0.2f * v);
                part = fmaf(v, attv[j], part);
            }
#pragma unroll
            for (int off = 8; off >= 1; off >>= 1)
                part += __shfl_xor(part, off, 64);
            float ex = __expf(fminf(part, 60.f));
            denom += ex;
#pragma unroll
            for (int j = 0; j < 4; ++j)
                acc[j] = fmaf(ex, lv[j], acc[j]);
        }
    }

    const float inv = 1.f / denom;
#pragma unroll
    for (int j = 0; j < 4; ++j) {
        acc[j] *= inv;
        acc[j] += __shfl_xor(acc[j], 16, 64);    // sum the 4 heads
        acc[j] += __shfl_xor(acc[j], 32, 64);
    }
    if (lane < 16) {
        const int fbo = flags[F_BO2];
        float4 o;
        float* op = (float*)&o;
#pragma unroll
        for (int j = 0; j < 4; ++j) {
            float v = acc[j] * 0.25f + ld_any(bo, lane * 4 + j, fbo);
            op[j] = (v > 0.f) ? v : 0.f;
        }
        *(float4*)(out + (size_t)d * 64 + lane * 4) = o;
    }
}

__global__ void plant_kernel(float* out, float code) {
    if (code > 0.f) out[0] = code;
}

extern "C" void kernel_launch(void* const* d_in, const int* in_sizes, int n_in,
                              void* d_out, int out_size, void* d_ws, size_t ws_size,
                              hipStream_t stream) {
    // ---- host-side slot mapping by element counts ----
    int ix = -1, iei = -1;
    int i4096[2], i16384[2], i64s[5], i256[3];
    int c4 = 0, c16 = 0, c64 = 0, c256 = 0;
    bool extra = false;
    for (int i = 0; i < n_in; ++i) {
        int sz = in_sizes[i];
        if (sz == 6400000)      { if (ix < 0) ix = i; else extra = true; }
        else if (sz == 3200000) { if (iei < 0) iei = i; else extra = true; }
        else if (sz == 4096)    { if (c4  < 2) i4096[c4]  = i; c4++;  }
        else if (sz == 16384)   { if (c16 < 2) i16384[c16] = i; c16++; }
        else if (sz == 64)      { if (c64 < 5) i64s[c64]  = i; c64++; }
        else if (sz == 256)     { if (c256 < 3) i256[c256] = i; c256++; }
        else if (sz == 100000 || sz == 1) { /* frame_mask / scalar: unused */ }
        else extra = true;
    }
    bool ok = (ix >= 0) && (iei >= 0) && (c4 == 2) && (c16 == 2)
              && (c64 == 5) && (c256 == 3) && !extra;
    float code = 0.f;
    if (!ok) {
        code = 50000.f + 100.f * (float)n_in;
        ix = 0; iei = 1;
        i4096[0] = 3;  i4096[1] = 5;
        i64s[0] = 4; i64s[1] = 6; i64s[2] = 7; i64s[3] = 8; i64s[4] = 14;
        i16384[0] = 9; i16384[1] = 11;
        i256[0] = 10; i256[1] = 12; i256[2] = 13;
    }

    const u16* x    = (const u16*)d_in[ix];
    const int* ei   = (const int*)d_in[iei];
    const u16* Wl1  = (const u16*)d_in[i4096[0]];
    const u16* Wr1  = (const u16*)d_in[i4096[1]];
    const u16* bl1  = (const u16*)d_in[i64s[0]];
    const u16* br1  = (const u16*)d_in[i64s[1]];
    const u16* att1 = (const u16*)d_in[i64s[2]];
    const u16* bo1  = (const u16*)d_in[i64s[3]];
    const u16* bo2  = (const u16*)d_in[i64s[4]];
    const u16* Wl2  = (const u16*)d_in[i16384[0]];
    const u16* Wr2  = (const u16*)d_in[i16384[1]];
    const u16* bl2  = (const u16*)d_in[i256[0]];
    const u16* br2  = (const u16*)d_in[i256[1]];
    const u16* att2 = (const u16*)d_in[i256[2]];

    // ---- workspace layout (bytes), ~136.1 MB ----
    char* ws = (char*)d_ws;
    u16* xlb     = (u16*)(ws);                    // N*256 bf16 = 51.2 MB
    u16* xrb     = (u16*)(ws + 51200000);         // N*256 bf16 = 51.2 MB
    u16* hbuf    = (u16*)(ws + 102400000);        // N*64  bf16 = 12.8 MB
    u16* xc      = (u16*)(ws + 115200000);        // N*64  bf16 = 12.8 MB
    int* row_ptr = (int*)(ws + 128000000);        // (N+1)*4
    int* cnt     = (int*)(ws + 128400016);        // N*4
    int* tmp     = (int*)(ws + 128800016);        // N*4
    int* bsum    = (int*)(ws + 129200016);        // NB*4
    int* csr_src = (int*)(ws + 129201600);        // EPLUS*4 = 6.8 MB
    u16* wt1l    = (u16*)(ws + 136001600);        // 64*64 bf16
    u16* wt1r    = (u16*)(ws + 136009792);
    u16* wt2l    = (u16*)(ws + 136017984);        // 256*64 bf16
    u16* wt2r    = (u16*)(ws + 136050752);
    u16* bcs     = (u16*)(ws + 136083520);        // 640 bf16
    int* flags   = (int*)(ws + 136084800);        // 16 ints
    const size_t need = 136084864;
    if (ws_size < need) {
        float c2 = 60000.f + (float)(ws_size >> 20);
        code = (c2 > code) ? c2 : code;
    }

    const int node_grid = (NNODES + 3) / 4;       // 25000
    const int ep_grid   = (EPLUS + 255) / 256;

    detect_all<<<1, 64, 0, stream>>>(x, Wl1, bl1, Wr1, br1, att1, bo1,
                                     Wl2, bl2, Wr2, br2, att2, bo2, ei, flags);

    // ---- canonicalize + histogram (one dispatch) ----
    (void)hipMemsetAsync(cnt, 0, (size_t)NNODES * 4, stream);
    conv_all<<<XB + WB + BB + HB, 256, 0, stream>>>(
        x, Wl1, Wr1, Wl2, Wr2, bl1, br1, bl2, br2, ei, flags,
        xc, wt1l, wt1r, wt2l, wt2r, bcs, cnt);

    // ---- CSR scan + fill ----
    scan1_kernel<<<NB, 256, 0, stream>>>(cnt, tmp, bsum);
    scan2_kernel<<<1, 512, 0, stream>>>(bsum);
    scan3_kernel<<<NB, 256, 0, stream>>>(tmp, bsum, row_ptr);
    (void)hipMemsetAsync(cnt, 0, (size_t)NNODES * 4, stream);
    fill_kernel<<<ep_grid, 256, 0, stream>>>(ei, flags, row_ptr, cnt, csr_src);

    // ---- layer 1 (64 -> 4x16, concat) ----
    gemm_mfma<64, 128><<<dim3((NNODES + 127) / 128, 2), 256, 0, stream>>>(
        xc, wt1l, wt1r, bcs, bcs + 64, xlb, xrb);
    gat_l1<<<node_grid, 256, 0, stream>>>(
        xlb, xrb, row_ptr, csr_src, att1, bo1, flags, hbuf);

    // ---- layer 2 (64 -> 4x64, mean) ----
    gemm_mfma<256, 64><<<dim3((NNODES + 63) / 64, 2), 256, 0, stream>>>(
        hbuf, wt2l, wt2r, bcs + 128, bcs + 384, xlb, xrb);
    gat_l2<<<node_grid, 256, 0, stream>>>(
        xlb, xrb, row_ptr, csr_src, att2, bo2, flags, (float*)d_out);

    plant_kernel<<<1, 1, 0, stream>>>((float*)d_out, code);
}

// Round 13
// 659.611 us; speedup vs baseline: 1.2208x; 1.0126x over previous
//
#include <hip/hip_runtime.h>
#include <hip/hip_bf16.h>
#include <cstdint>
#include <cstddef>

#define NNODES 100000
#define NEDGES 1600000
#define EPLUS  (NEDGES + NNODES)   // edges + self loops
#define NHEADS 4
#define NB     ((NNODES + 255) / 256)   // 391 scan blocks

typedef __hip_bfloat16 bf16;
typedef unsigned short u16;
typedef __attribute__((ext_vector_type(8))) short bf16x8;
typedef __attribute__((ext_vector_type(4))) float f32x4;
typedef __attribute__((ext_vector_type(2))) float v2f;

// flag indices
#define F_X    0
#define F_WL1  1
#define F_BL1  2
#define F_WR1  3
#define F_BR1  4
#define F_ATT1 5
#define F_BO1  6
#define F_WL2  7
#define F_BL2  8
#define F_WR2  9
#define F_BR2  10
#define F_ATT2 11
#define F_BO2  12
#define F_EI64 13

__device__ __forceinline__ float u2f(u16 s) { return __uint_as_float(((unsigned)s) << 16); }
__device__ __forceinline__ u16  f2u(float f) {
    return __bfloat16_as_ushort(__float2bfloat16(f));
}
__device__ __forceinline__ float ld_any(const void* p, long i, int f32) {
    return f32 ? ((const float*)p)[i] : u2f(((const u16*)p)[i]);
}
// bf16 pair (packed dword) -> two f32
__device__ __forceinline__ v2f cvt2(unsigned p) {
    v2f r;
    r.x = __uint_as_float(p << 16);
    r.y = __uint_as_float(p & 0xffff0000u);
    return r;
}

// ---- dtype detection for every float tensor + edge_index width ------------
__global__ void detect_all(const u16* x, const u16* Wl1, const u16* bl1,
                           const u16* Wr1, const u16* br1, const u16* att1,
                           const u16* bo1, const u16* Wl2, const u16* bl2,
                           const u16* Wr2, const u16* br2, const u16* att2,
                           const u16* bo2, const int* ei, int* flags) {
    const int t = threadIdx.x;
    const u16* ptrs[13] = {x, Wl1, bl1, Wr1, br1, att1, bo1,
                           Wl2, bl2, Wr2, br2, att2, bo2};
    const int cnts[13] = {NNODES * 64, 64 * 64, 64, 64 * 64, 64, 64, 64,
                          64 * 256, 256, 64 * 256, 256, 256, 64};
    if (t < 13) {
        const u16* p = ptrs[t];
        const int cnt = cnts[t];
        int weird = 0, n = 0;
        for (int k = 0; k < 128; ++k) {
            int idx = 2 * k;
            if (idx >= cnt) break;
            u16 v = p[idx];
            n++;
            int ex = (v >> 7) & 0xFF;
            if (v != 0 && (ex < 96 || ex > 143)) weird++;
        }
        flags[t] = (weird * 4 > n) ? 1 : 0;   // 1 => f32
    } else if (t == 13) {
        int any = 0;
        for (int k = 0; k < 64; ++k) any |= ei[2 * k + 1];
        flags[F_EI64] = (any == 0) ? 1 : 0;   // 1 => int64
    }
}

__device__ __forceinline__ void edge_sd(const int* __restrict__ ei, int i64,
                                        int e, int& s, int& d) {
    if (e >= NEDGES) { s = d = e - NEDGES; return; }   // self loop
    if (i64) {
        const long long* p = (const long long*)ei;
        s = (int)p[e]; d = (int)p[NEDGES + e];
    } else {
        s = ei[e]; d = ei[NEDGES + e];
    }
    s = min(max(s, 0), NNODES - 1);
    d = min(max(d, 0), NNODES - 1);
}

// ---- mega conv kernel: xc convert + 4 weight transposes + biases + hist ---
#define XB 6250            // xc blocks (4 elems/thread)
#define WB 160             // weight blocks (40960 elems)
#define BB 3               // bias blocks
#define HB 6250            // hist blocks
__global__ __launch_bounds__(256)
void conv_all(const void* __restrict__ x,
              const void* __restrict__ Wl1, const void* __restrict__ Wr1,
              const void* __restrict__ Wl2, const void* __restrict__ Wr2,
              const void* __restrict__ bl1, const void* __restrict__ br1,
              const void* __restrict__ bl2, const void* __restrict__ br2,
              const int* __restrict__ ei, const int* __restrict__ flags,
              u16* __restrict__ xc, u16* __restrict__ wt1l, u16* __restrict__ wt1r,
              u16* __restrict__ wt2l, u16* __restrict__ wt2r,
              u16* __restrict__ bcs, int* __restrict__ cnt) {
    int b = blockIdx.x;
    if (b < XB) {                       // ---- xc: bf16 canonical copy of x
        const long i4 = ((long)b * 256 + threadIdx.x) * 4;
        if (i4 < (long)NNODES * 64) {
            if (flags[F_X]) {
                const float4 v = *(const float4*)((const float*)x + i4);
                ushort4 o; o.x=f2u(v.x); o.y=f2u(v.y); o.z=f2u(v.z); o.w=f2u(v.w);
                *(ushort4*)(xc + i4) = o;
            } else {
                *(ushort4*)(xc + i4) = *(const ushort4*)((const u16*)x + i4);
            }
        }
        return;
    }
    b -= XB;
    if (b < WB) {                       // ---- weight transposes W[64][M]->Wt[M][64]
        const int e = b * 256 + threadIdx.x;
        const void* W; u16* wt; int M, fwi, local;
        if (e < 4096)        { W = Wl1; wt = wt1l; M = 64;  fwi = F_WL1; local = e; }
        else if (e < 8192)   { W = Wr1; wt = wt1r; M = 64;  fwi = F_WR1; local = e - 4096; }
        else if (e < 24576)  { W = Wl2; wt = wt2l; M = 256; fwi = F_WL2; local = e - 8192; }
        else                 { W = Wr2; wt = wt2r; M = 256; fwi = F_WR2; local = e - 24576; }
        const int m = local >> 6, k = local & 63;
        wt[local] = f2u(ld_any(W, (long)k * M + m, flags[fwi]));
        return;
    }
    b -= WB;
    if (b < BB) {                       // ---- biases into bcs[640]
        const int t = b * 256 + threadIdx.x;
        if (t < 64)       bcs[t] = f2u(ld_any(bl1, t,       flags[F_BL1]));
        else if (t < 128) bcs[t] = f2u(ld_any(br1, t - 64,  flags[F_BR1]));
        else if (t < 384) bcs[t] = f2u(ld_any(bl2, t - 128, flags[F_BL2]));
        else if (t < 640) bcs[t] = f2u(ld_any(br2, t - 384, flags[F_BR2]));
        return;
    }
    b -= BB;
    {                                   // ---- dst histogram
        const int e = b * 256 + threadIdx.x;
        if (e >= NEDGES) return;
        int d;
        if (flags[F_EI64]) d = (int)((const long long*)ei)[NEDGES + e];
        else               d = ei[NEDGES + e];
        d = min(max(d, 0), NNODES - 1);
        atomicAdd(&cnt[d], 1);
    }
}

// ---------------- CSR scan / fill ------------------------------------------
__global__ __launch_bounds__(256)
void scan1_kernel(const int* __restrict__ cnt, int* __restrict__ tmp,
                  int* __restrict__ bsum) {
    __shared__ int sh[256];
    const int idx = blockIdx.x * 256 + threadIdx.x;
    int v = (idx < NNODES) ? cnt[idx] + 1 : 0;
    sh[threadIdx.x] = v;
    __syncthreads();
    for (int off = 1; off < 256; off <<= 1) {
        int t = (threadIdx.x >= off) ? sh[threadIdx.x - off] : 0;
        __syncthreads();
        sh[threadIdx.x] += t;
        __syncthreads();
    }
    if (idx < NNODES) tmp[idx] = sh[threadIdx.x];
    if (threadIdx.x == 255) bsum[blockIdx.x] = sh[255];
}

__global__ __launch_bounds__(512)
void scan2_kernel(int* __restrict__ bsum) {
    __shared__ int sh[512];
    const int t = threadIdx.x;
    sh[t] = (t < NB) ? bsum[t] : 0;
    __syncthreads();
    for (int off = 1; off < 512; off <<= 1) {
        int v = (t >= off) ? sh[t - off] : 0;
        __syncthreads();
        sh[t] += v;
        __syncthreads();
    }
    if (t < NB) bsum[t] = sh[t];
}

__global__ __launch_bounds__(256)
void scan3_kernel(const int* __restrict__ tmp, const int* __restrict__ bsum,
                  int* __restrict__ row_ptr) {
    const int idx = blockIdx.x * 256 + threadIdx.x;
    if (idx < NNODES) {
        int off = (blockIdx.x > 0) ? bsum[blockIdx.x - 1] : 0;
        row_ptr[idx + 1] = tmp[idx] + off;
    }
    if (idx == 0) row_ptr[0] = 0;
}

__global__ __launch_bounds__(256)
void fill_kernel(const int* __restrict__ ei, const int* __restrict__ flags,
                 const int* __restrict__ row_ptr, int* __restrict__ cur,
                 int* __restrict__ csr_src) {
    const int e = blockIdx.x * 256 + threadIdx.x;
    if (e >= EPLUS) return;
    int s, d;
    edge_sd(ei, flags[F_EI64], e, s, d);
    int slot = row_ptr[d] + atomicAdd(&cur[d], 1);
    csr_src[slot] = s;
}

// ---------------- MFMA GEMM: both l/r transforms in one dispatch -----------
template<int M, int RPB>
__global__ __launch_bounds__(256)
void gemm_mfma(const u16* __restrict__ xc,
               const u16* __restrict__ wtl, const u16* __restrict__ wtr,
               const u16* __restrict__ bcl, const u16* __restrict__ bcr,
               u16* __restrict__ outl, u16* __restrict__ outr) {
    constexpr int MT = RPB / 16;
    constexpr int NT = M / 64;
    const u16* wt = blockIdx.y ? wtr : wtl;
    const u16* bc = blockIdx.y ? bcr : bcl;
    u16* out      = blockIdx.y ? outr : outl;
    const int wave = threadIdx.x >> 6;
    const int lane = threadIdx.x & 63;
    const int quad = lane >> 4;
    const int l16  = lane & 15;
    const int row0 = blockIdx.x * RPB;
    const int col0 = wave * (M / 4);

    bf16x8 bfrag[NT][2];
#pragma unroll
    for (int nt = 0; nt < NT; ++nt)
#pragma unroll
        for (int c = 0; c < 2; ++c)
            bfrag[nt][c] = *(const bf16x8*)(wt +
                ((size_t)(col0 + nt * 16 + l16) * 64 + c * 32 + quad * 8));

    f32x4 acc[MT][NT];
#pragma unroll
    for (int mt = 0; mt < MT; ++mt)
#pragma unroll
        for (int nt = 0; nt < NT; ++nt)
            acc[mt][nt] = f32x4{0.f, 0.f, 0.f, 0.f};

#pragma unroll
    for (int mt = 0; mt < MT; ++mt) {
        int row = row0 + mt * 16 + l16;
        row = (row < NNODES) ? row : (NNODES - 1);
#pragma unroll
        for (int c = 0; c < 2; ++c) {
            bf16x8 afrag = *(const bf16x8*)(xc + ((size_t)row * 64 + c * 32 + quad * 8));
#pragma unroll
            for (int nt = 0; nt < NT; ++nt)
                acc[mt][nt] = __builtin_amdgcn_mfma_f32_16x16x32_bf16(
                    afrag, bfrag[nt][c], acc[mt][nt], 0, 0, 0);
        }
    }

#pragma unroll
    for (int mt = 0; mt < MT; ++mt) {
#pragma unroll
        for (int nt = 0; nt < NT; ++nt) {
            const int col = col0 + nt * 16 + l16;
            const float bias = u2f(bc[col]);
#pragma unroll
            for (int r = 0; r < 4; ++r) {
                const int row = row0 + mt * 16 + quad * 4 + r;
                if (row < NNODES)
                    out[(size_t)row * M + col] = f2u(acc[mt][nt][r] + bias);
            }
        }
    }
}

// ------- layer-1 fused GAT: 4 edges per wave-iteration (R12-proven) --------
__global__ __launch_bounds__(256)
void gat_l1(const u16* __restrict__ xl, const u16* __restrict__ xr,
            const int* __restrict__ row_ptr, const int* __restrict__ csr_src,
            const void* __restrict__ att, const void* __restrict__ bo,
            const int* __restrict__ flags, u16* __restrict__ out) {
    const int d = blockIdx.x * 4 + (threadIdx.x >> 6);
    if (d >= NNODES) return;
    const int lane = threadIdx.x & 63;
    const int q = lane >> 4;
    const int l = lane & 15;
    const int fatt = flags[F_ATT1];

    float attv[4], rv[4];
#pragma unroll
    for (int j = 0; j < 4; ++j)
        attv[j] = ld_any(att, l * 4 + j, fatt);
    {
        ushort4 r = *(const ushort4*)(xr + (size_t)d * 64 + l * 4);
        rv[0]=u2f(r.x); rv[1]=u2f(r.y); rv[2]=u2f(r.z); rv[3]=u2f(r.w);
    }

    const int beg = row_ptr[d], end = row_ptr[d + 1];
    float denom = 1e-16f;
    float acc[4] = {0.f, 0.f, 0.f, 0.f};

    ushort4 a4;
    {
        int e0 = beg + q;
        int idx = (e0 < end) ? e0 : (end - 1);
        a4 = *(const ushort4*)(xl + (size_t)csr_src[idx] * 64 + l * 4);
    }

    for (int base = beg; base < end; base += 4) {
        float lv[4];
        lv[0]=u2f(a4.x); lv[1]=u2f(a4.y); lv[2]=u2f(a4.z); lv[3]=u2f(a4.w);
        if (base + 4 < end) {
            int en = base + 4 + q;
            int idx = (en < end) ? en : (end - 1);
            a4 = *(const ushort4*)(xl + (size_t)csr_src[idx] * 64 + l * 4);
        }
        float part = 0.f;
#pragma unroll
        for (int j = 0; j < 4; ++j) {
            float v = lv[j] + rv[j];
            v = fmaxf(v, 0.2f * v);
            part = fmaf(v, attv[j], part);
        }
        part += __shfl_xor(part, 1, 64);         // head reduce (4 lanes)
        part += __shfl_xor(part, 2, 64);
        float ex = __expf(fminf(part, 60.f));
        ex = (base + q < end) ? ex : 0.f;        // mask invalid slots
        denom += ex;
#pragma unroll
        for (int j = 0; j < 4; ++j)
            acc[j] = fmaf(ex, lv[j], acc[j]);
    }

    denom += __shfl_xor(denom, 16, 64);          // combine the 4 edge slots
    denom += __shfl_xor(denom, 32, 64);
#pragma unroll
    for (int j = 0; j < 4; ++j) {
        acc[j] += __shfl_xor(acc[j], 16, 64);
        acc[j] += __shfl_xor(acc[j], 32, 64);
    }
    const float inv = 1.f / denom;

    if (lane < 16) {                             // lanes 0-15: channels 4l..4l+3
        const int fbo = flags[F_BO1];
        ushort4 o;
        u16* op = (u16*)&o;
#pragma unroll
        for (int j = 0; j < 4; ++j) {
            float v = acc[j] * inv + ld_any(bo, l * 4 + j, fbo);
            op[j] = f2u((v > 0.f) ? v : 0.f);
        }
        *(ushort4*)(out + (size_t)d * 64 + l * 4) = o;
    }
}

// ------- layer-2 fused GAT: 2 edges/wave, 32 lanes/edge, 8 ch/lane ---------
// half = lane>>5 selects the edge; lane&31 holds channels 8l..8l+7 via one
// uint4 (b128) load. Head = (lane&31)>>3 (8 lanes); reduce = 3 shuffles
// SHARED by both edges. Elementwise math in float2 (v_pk_*_f32).
__global__ __launch_bounds__(256)
void gat_l2(const u16* __restrict__ xl, const u16* __restrict__ xr,
            const int* __restrict__ row_ptr, const int* __restrict__ csr_src,
            const void* __restrict__ att, const void* __restrict__ bo,
            const int* __restrict__ flags, float* __restrict__ out) {
    const int d = blockIdx.x * 4 + (threadIdx.x >> 6);
    if (d >= NNODES) return;
    const int lane = threadIdx.x & 63;
    const int half = lane >> 5;
    const int l    = lane & 31;          // channels 8l..8l+7
    const int fatt = flags[F_ATT2];

    v2f attv[4], rv[4];
#pragma unroll
    for (int j = 0; j < 4; ++j) {
        v2f a;
        a.x = ld_any(att, l * 8 + 2 * j,     fatt);
        a.y = ld_any(att, l * 8 + 2 * j + 1, fatt);
        attv[j] = a;
    }
    {
        uint4 r = *(const uint4*)(xr + (size_t)d * 256 + l * 8);
        rv[0] = cvt2(r.x); rv[1] = cvt2(r.y); rv[2] = cvt2(r.z); rv[3] = cvt2(r.w);
    }

    const int beg = row_ptr[d], end = row_ptr[d + 1];   // end > beg (self loop)
    float denom = 1e-16f;
    v2f acc[4];
#pragma unroll
    for (int j = 0; j < 4; ++j) acc[j] = (v2f){0.f, 0.f};

    uint4 raw;
    {
        int idx = beg + half;
        idx = (idx < end) ? idx : (end - 1);
        raw = *(const uint4*)(xl + (size_t)csr_src[idx] * 256 + l * 8);
    }

    for (int base = beg; base < end; base += 2) {
        v2f lv[4];
        lv[0] = cvt2(raw.x); lv[1] = cvt2(raw.y);
        lv[2] = cvt2(raw.z); lv[3] = cvt2(raw.w);
        if (base + 2 < end) {                    // prefetch next edge pair
            int idx = base + 2 + half;
            idx = (idx < end) ? idx : (end - 1);
            raw = *(const uint4*)(xl + (size_t)csr_src[idx] * 256 + l * 8);
        }
        v2f p = (v2f){0.f, 0.f};
#pragma unroll
        for (int j = 0; j < 4; ++j) {
            v2f v = lv[j] + rv[j];
            v2f t = v * 0.2f;                    // leaky_relu
            v.x = fmaxf(v.x, t.x);
            v.y = fmaxf(v.y, t.y);
            p += v * attv[j];                    // pk_fma
        }
        float part = p.x + p.y;
        part += __shfl_xor(part, 1, 64);         // head reduce (8 lanes),
        part += __shfl_xor(part, 2, 64);         // shared by both edges
        part += __shfl_xor(part, 4, 64);
        float ex = __expf(fminf(part, 60.f));
        ex = (base + half < end) ? ex : 0.f;     // mask invalid second slot
        denom += ex;
#pragma unroll
        for (int j = 0; j < 4; ++j)
            acc[j] += lv[j] * ex;                // pk_fma
    }

    // combine the two edge halves (lanes l and l+32 share channels)
    denom += __shfl_xor(denom, 32, 64);
#pragma unroll
    for (int j = 0; j < 4; ++j) {
        acc[j].x += __shfl_xor(acc[j].x, 32, 64);
        acc[j].y += __shfl_xor(acc[j].y, 32, 64);
    }
    const float inv = 1.f / denom;               // full denom of this head
#pragma unroll
    for (int j = 0; j < 4; ++j) {
        acc[j] *= inv;
        acc[j].x += __shfl_xor(acc[j].x, 8, 64); // sum the 4 heads:
        acc[j].y += __shfl_xor(acc[j].y, 8, 64); // lanes l, l^8, l^16, l^24
        acc[j].x += __shfl_xor(acc[j].x, 16, 64);
        acc[j].y += __shfl_xor(acc[j].y, 16, 64);
    }
    if (lane < 8) {                              // lanes 0-7: channels 8l..8l+7
        const int fbo = flags[F_BO2];
        float vv[8];
#pragma unroll
        for (int j = 0; j < 4; ++j) { vv[2*j] = acc[j].x; vv[2*j+1] = acc[j].y; }
#pragma unroll
        for (int k = 0; k < 8; ++k) {
            float v = vv[k] * 0.25f + ld_any(bo, l * 8 + k, fbo);
            vv[k] = (v > 0.f) ? v : 0.f;
        }
        float* po = out + (size_t)d * 64 + l * 8;
        *(float4*)po       = make_float4(vv[0], vv[1], vv[2], vv[3]);
        *(float4*)(po + 4) = make_float4(vv[4], vv[5], vv[6], vv[7]);
    }
}

__global__ void plant_kernel(float* out, float code) {
    if (code > 0.f) out[0] = code;
}

extern "C" void kernel_launch(void* const* d_in, const int* in_sizes, int n_in,
                              void* d_out, int out_size, void* d_ws, size_t ws_size,
                              hipStream_t stream) {
    // ---- host-side slot mapping by element counts ----
    int ix = -1, iei = -1;
    int i4096[2], i16384[2], i64s[5], i256[3];
    int c4 = 0, c16 = 0, c64 = 0, c256 = 0;
    bool extra = false;
    for (int i = 0; i < n_in; ++i) {
        int sz = in_sizes[i];
        if (sz == 6400000)      { if (ix < 0) ix = i; else extra = true; }
        else if (sz == 3200000) { if (iei < 0) iei = i; else extra = true; }
        else if (sz == 4096)    { if (c4  < 2) i4096[c4]  = i; c4++;  }
        else if (sz == 16384)   { if (c16 < 2) i16384[c16] = i; c16++; }
        else if (sz == 64)      { if (c64 < 5) i64s[c64]  = i; c64++; }
        else if (sz == 256)     { if (c256 < 3) i256[c256] = i; c256++; }
        else if (sz == 100000 || sz == 1) { /* frame_mask / scalar: unused */ }
        else extra = true;
    }
    bool ok = (ix >= 0) && (iei >= 0) && (c4 == 2) && (c16 == 2)
              && (c64 == 5) && (c256 == 3) && !extra;
    float code = 0.f;
    if (!ok) {
        code = 50000.f + 100.f * (float)n_in;
        ix = 0; iei = 1;
        i4096[0] = 3;  i4096[1] = 5;
        i64s[0] = 4; i64s[1] = 6; i64s[2] = 7; i64s[3] = 8; i64s[4] = 14;
        i16384[0] = 9; i16384[1] = 11;
        i256[0] = 10; i256[1] = 12; i256[2] = 13;
    }

    const u16* x    = (const u16*)d_in[ix];
    const int* ei   = (const int*)d_in[iei];
    const u16* Wl1  = (const u16*)d_in[i4096[0]];
    const u16* Wr1  = (const u16*)d_in[i4096[1]];
    const u16* bl1  = (const u16*)d_in[i64s[0]];
    const u16* br1  = (const u16*)d_in[i64s[1]];
    const u16* att1 = (const u16*)d_in[i64s[2]];
    const u16* bo1  = (const u16*)d_in[i64s[3]];
    const u16* bo2  = (const u16*)d_in[i64s[4]];
    const u16* Wl2  = (const u16*)d_in[i16384[0]];
    const u16* Wr2  = (const u16*)d_in[i16384[1]];
    const u16* bl2  = (const u16*)d_in[i256[0]];
    const u16* br2  = (const u16*)d_in[i256[1]];
    const u16* att2 = (const u16*)d_in[i256[2]];

    // ---- workspace layout (bytes), ~136.1 MB ----
    char* ws = (char*)d_ws;
    u16* xlb     = (u16*)(ws);                    // N*256 bf16 = 51.2 MB
    u16* xrb     = (u16*)(ws + 51200000);         // N*256 bf16 = 51.2 MB
    u16* hbuf    = (u16*)(ws + 102400000);        // N*64  bf16 = 12.8 MB
    u16* xc      = (u16*)(ws + 115200000);        // N*64  bf16 = 12.8 MB
    int* row_ptr = (int*)(ws + 128000000);        // (N+1)*4
    int* cnt     = (int*)(ws + 128400016);        // N*4
    int* tmp     = (int*)(ws + 128800016);        // N*4
    int* bsum    = (int*)(ws + 129200016);        // NB*4
    int* csr_src = (int*)(ws + 129201600);        // EPLUS*4 = 6.8 MB
    u16* wt1l    = (u16*)(ws + 136001600);        // 64*64 bf16
    u16* wt1r    = (u16*)(ws + 136009792);
    u16* wt2l    = (u16*)(ws + 136017984);        // 256*64 bf16
    u16* wt2r    = (u16*)(ws + 136050752);
    u16* bcs     = (u16*)(ws + 136083520);        // 640 bf16
    int* flags   = (int*)(ws + 136084800);        // 16 ints
    const size_t need = 136084864;
    if (ws_size < need) {
        float c2 = 60000.f + (float)(ws_size >> 20);
        code = (c2 > code) ? c2 : code;
    }

    const int node_grid = (NNODES + 3) / 4;       // 25000
    const int ep_grid   = (EPLUS + 255) / 256;

    detect_all<<<1, 64, 0, stream>>>(x, Wl1, bl1, Wr1, br1, att1, bo1,
                                     Wl2, bl2, Wr2, br2, att2, bo2, ei, flags);

    // ---- canonicalize + histogram (one dispatch) ----
    (void)hipMemsetAsync(cnt, 0, (size_t)NNODES * 4, stream);
    conv_all<<<XB + WB + BB + HB, 256, 0, stream>>>(
        x, Wl1, Wr1, Wl2, Wr2, bl1, br1, bl2, br2, ei, flags,
        xc, wt1l, wt1r, wt2l, wt2r, bcs, cnt);

    // ---- CSR scan + fill ----
    scan1_kernel<<<NB, 256, 0, stream>>>(cnt, tmp, bsum);
    scan2_kernel<<<1, 512, 0, stream>>>(bsum);
    scan3_kernel<<<NB, 256, 0, stream>>>(tmp, bsum, row_ptr);
    (void)hipMemsetAsync(cnt, 0, (size_t)NNODES * 4, stream);
    fill_kernel<<<ep_grid, 256, 0, stream>>>(ei, flags, row_ptr, cnt, csr_src);

    // ---- layer 1 (64 -> 4x16, concat) ----
    gemm_mfma<64, 128><<<dim3((NNODES + 127) / 128, 2), 256, 0, stream>>>(
        xc, wt1l, wt1r, bcs, bcs + 64, xlb, xrb);
    gat_l1<<<node_grid, 256, 0, stream>>>(
        xlb, xrb, row_ptr, csr_src, att1, bo1, flags, hbuf);

    // ---- layer 2 (64 -> 4x64, mean) ----
    gemm_mfma<256, 64><<<dim3((NNODES + 63) / 64, 2), 256, 0, stream>>>(
        hbuf, wt2l, wt2r, bcs + 128, bcs + 384, xlb, xrb);
    gat_l2<<<node_grid, 256, 0, stream>>>(
        xlb, xrb, row_ptr, csr_src, att2, bo2, flags, (float*)d_out);

    plant_kernel<<<1, 1, 0, stream>>>((float*)d_out, code);
}

// Round 14
// 630.569 us; speedup vs baseline: 1.2770x; 1.0461x over previous
//
#include <hip/hip_runtime.h>
#include <hip/hip_bf16.h>
#include <cstdint>
#include <cstddef>

#define NNODES 100000
#define NEDGES 1600000
#define EPLUS  (NEDGES + NNODES)   // edges + self loops
#define NHEADS 4
#define NB     ((NNODES + 255) / 256)   // 391 scan blocks

typedef __hip_bfloat16 bf16;
typedef unsigned short u16;
typedef __attribute__((ext_vector_type(8))) short bf16x8;
typedef __attribute__((ext_vector_type(4))) float f32x4;
typedef __attribute__((ext_vector_type(2))) float v2f;

// flag indices
#define F_X    0
#define F_WL1  1
#define F_BL1  2
#define F_WR1  3
#define F_BR1  4
#define F_ATT1 5
#define F_BO1  6
#define F_WL2  7
#define F_BL2  8
#define F_WR2  9
#define F_BR2  10
#define F_ATT2 11
#define F_BO2  12
#define F_EI64 13

__device__ __forceinline__ float u2f(u16 s) { return __uint_as_float(((unsigned)s) << 16); }
__device__ __forceinline__ u16  f2u(float f) {
    return __bfloat16_as_ushort(__float2bfloat16(f));
}
__device__ __forceinline__ float ld_any(const void* p, long i, int f32) {
    return f32 ? ((const float*)p)[i] : u2f(((const u16*)p)[i]);
}
// bf16 pair (packed dword) -> two f32
__device__ __forceinline__ v2f cvt2(unsigned p) {
    v2f r;
    r.x = __uint_as_float(p << 16);
    r.y = __uint_as_float(p & 0xffff0000u);
    return r;
}

// ---- dtype detection: one 64-thread block per tensor (parallel) -----------
__global__ void detect_all(const u16* x, const u16* Wl1, const u16* bl1,
                           const u16* Wr1, const u16* br1, const u16* att1,
                           const u16* bo1, const u16* Wl2, const u16* bl2,
                           const u16* Wr2, const u16* br2, const u16* att2,
                           const u16* bo2, const int* ei, int* flags) {
    const int b = blockIdx.x;
    const int k = threadIdx.x;
    if (b < 13) {
        const u16* ptrs[13] = {x, Wl1, bl1, Wr1, br1, att1, bo1,
                               Wl2, bl2, Wr2, br2, att2, bo2};
        const int cnts[13] = {NNODES * 64, 64 * 64, 64, 64 * 64, 64, 64, 64,
                              64 * 256, 256, 64 * 256, 256, 256, 64};
        const u16* p = ptrs[b];
        const int cnt = cnts[b];
        int weird = 0, n = 0;
#pragma unroll
        for (int s = 0; s < 2; ++s) {
            int idx = 2 * (k + 64 * s);
            if (idx < cnt) {
                n++;
                u16 v = p[idx];
                int ex = (v >> 7) & 0xFF;
                if (v != 0 && (ex < 96 || ex > 143)) weird++;
            }
        }
        // wave-wide sums via ballot-free shuffle reduce
        int w = weird, m = n;
#pragma unroll
        for (int off = 32; off >= 1; off >>= 1) {
            w += __shfl_xor(w, off, 64);
            m += __shfl_xor(m, off, 64);
        }
        if (k == 0) flags[b] = (w * 4 > m) ? 1 : 0;   // 1 => f32
    } else {
        int any = ei[2 * k + 1];
#pragma unroll
        for (int off = 32; off >= 1; off >>= 1)
            any |= __shfl_xor(any, off, 64);
        if (k == 0) flags[F_EI64] = (any == 0) ? 1 : 0;   // 1 => int64
    }
}

__device__ __forceinline__ void edge_sd(const int* __restrict__ ei, int i64,
                                        int e, int& s, int& d) {
    if (e >= NEDGES) { s = d = e - NEDGES; return; }   // self loop
    if (i64) {
        const long long* p = (const long long*)ei;
        s = (int)p[e]; d = (int)p[NEDGES + e];
    } else {
        s = ei[e]; d = ei[NEDGES + e];
    }
    s = min(max(s, 0), NNODES - 1);
    d = min(max(d, 0), NNODES - 1);
}

// ---- mega conv kernel: xc convert + 4 weight transposes + biases + hist ---
#define XB 6250            // xc blocks (4 elems/thread)
#define WB 160             // weight blocks (40960 elems)
#define BB 3               // bias blocks
#define HB 6250            // hist blocks
__global__ __launch_bounds__(256)
void conv_all(const void* __restrict__ x,
              const void* __restrict__ Wl1, const void* __restrict__ Wr1,
              const void* __restrict__ Wl2, const void* __restrict__ Wr2,
              const void* __restrict__ bl1, const void* __restrict__ br1,
              const void* __restrict__ bl2, const void* __restrict__ br2,
              const int* __restrict__ ei, const int* __restrict__ flags,
              u16* __restrict__ xc, u16* __restrict__ wt1l, u16* __restrict__ wt1r,
              u16* __restrict__ wt2l, u16* __restrict__ wt2r,
              u16* __restrict__ bcs, int* __restrict__ cnt) {
    int b = blockIdx.x;
    if (b < XB) {                       // ---- xc: bf16 canonical copy of x
        const long i4 = ((long)b * 256 + threadIdx.x) * 4;
        if (i4 < (long)NNODES * 64) {
            if (flags[F_X]) {
                const float4 v = *(const float4*)((const float*)x + i4);
                ushort4 o; o.x=f2u(v.x); o.y=f2u(v.y); o.z=f2u(v.z); o.w=f2u(v.w);
                *(ushort4*)(xc + i4) = o;
            } else {
                *(ushort4*)(xc + i4) = *(const ushort4*)((const u16*)x + i4);
            }
        }
        return;
    }
    b -= XB;
    if (b < WB) {                       // ---- weight transposes W[64][M]->Wt[M][64]
        const int e = b * 256 + threadIdx.x;
        const void* W; u16* wt; int M, fwi, local;
        if (e < 4096)        { W = Wl1; wt = wt1l; M = 64;  fwi = F_WL1; local = e; }
        else if (e < 8192)   { W = Wr1; wt = wt1r; M = 64;  fwi = F_WR1; local = e - 4096; }
        else if (e < 24576)  { W = Wl2; wt = wt2l; M = 256; fwi = F_WL2; local = e - 8192; }
        else                 { W = Wr2; wt = wt2r; M = 256; fwi = F_WR2; local = e - 24576; }
        const int m = local >> 6, k = local & 63;
        wt[local] = f2u(ld_any(W, (long)k * M + m, flags[fwi]));
        return;
    }
    b -= WB;
    if (b < BB) {                       // ---- biases into bcs[640]
        const int t = b * 256 + threadIdx.x;
        if (t < 64)       bcs[t] = f2u(ld_any(bl1, t,       flags[F_BL1]));
        else if (t < 128) bcs[t] = f2u(ld_any(br1, t - 64,  flags[F_BR1]));
        else if (t < 384) bcs[t] = f2u(ld_any(bl2, t - 128, flags[F_BL2]));
        else if (t < 640) bcs[t] = f2u(ld_any(br2, t - 384, flags[F_BR2]));
        return;
    }
    b -= BB;
    {                                   // ---- dst histogram
        const int e = b * 256 + threadIdx.x;
        if (e >= NEDGES) return;
        int d;
        if (flags[F_EI64]) d = (int)((const long long*)ei)[NEDGES + e];
        else               d = ei[NEDGES + e];
        d = min(max(d, 0), NNODES - 1);
        atomicAdd(&cnt[d], 1);
    }
}

// ---------------- CSR scan / fill ------------------------------------------
__global__ __launch_bounds__(256)
void scan1_kernel(const int* __restrict__ cnt, int* __restrict__ tmp,
                  int* __restrict__ bsum) {
    __shared__ int sh[256];
    const int idx = blockIdx.x * 256 + threadIdx.x;
    int v = (idx < NNODES) ? cnt[idx] + 1 : 0;
    sh[threadIdx.x] = v;
    __syncthreads();
    for (int off = 1; off < 256; off <<= 1) {
        int t = (threadIdx.x >= off) ? sh[threadIdx.x - off] : 0;
        __syncthreads();
        sh[threadIdx.x] += t;
        __syncthreads();
    }
    if (idx < NNODES) tmp[idx] = sh[threadIdx.x];
    if (threadIdx.x == 255) bsum[blockIdx.x] = sh[255];
}

__global__ __launch_bounds__(512)
void scan2_kernel(int* __restrict__ bsum) {
    __shared__ int sh[512];
    const int t = threadIdx.x;
    sh[t] = (t < NB) ? bsum[t] : 0;
    __syncthreads();
    for (int off = 1; off < 512; off <<= 1) {
        int v = (t >= off) ? sh[t - off] : 0;
        __syncthreads();
        sh[t] += v;
        __syncthreads();
    }
    if (t < NB) bsum[t] = sh[t];
}

__global__ __launch_bounds__(256)
void scan3_kernel(const int* __restrict__ tmp, const int* __restrict__ bsum,
                  int* __restrict__ row_ptr) {
    const int idx = blockIdx.x * 256 + threadIdx.x;
    if (idx < NNODES) {
        int off = (blockIdx.x > 0) ? bsum[blockIdx.x - 1] : 0;
        row_ptr[idx + 1] = tmp[idx] + off;
    }
    if (idx == 0) row_ptr[0] = 0;
}

__global__ __launch_bounds__(256)
void fill_kernel(const int* __restrict__ ei, const int* __restrict__ flags,
                 const int* __restrict__ row_ptr, int* __restrict__ cur,
                 int* __restrict__ csr_src) {
    const int e = blockIdx.x * 256 + threadIdx.x;
    if (e >= EPLUS) return;
    int s, d;
    edge_sd(ei, flags[F_EI64], e, s, d);
    int slot = row_ptr[d] + atomicAdd(&cur[d], 1);
    csr_src[slot] = s;
}

// ---------------- MFMA GEMM: both l/r transforms in one dispatch -----------
template<int M, int RPB>
__global__ __launch_bounds__(256)
void gemm_mfma(const u16* __restrict__ xc,
               const u16* __restrict__ wtl, const u16* __restrict__ wtr,
               const u16* __restrict__ bcl, const u16* __restrict__ bcr,
               u16* __restrict__ outl, u16* __restrict__ outr) {
    constexpr int MT = RPB / 16;
    constexpr int NT = M / 64;
    const u16* wt = blockIdx.y ? wtr : wtl;
    const u16* bc = blockIdx.y ? bcr : bcl;
    u16* out      = blockIdx.y ? outr : outl;
    const int wave = threadIdx.x >> 6;
    const int lane = threadIdx.x & 63;
    const int quad = lane >> 4;
    const int l16  = lane & 15;
    const int row0 = blockIdx.x * RPB;
    const int col0 = wave * (M / 4);

    bf16x8 bfrag[NT][2];
#pragma unroll
    for (int nt = 0; nt < NT; ++nt)
#pragma unroll
        for (int c = 0; c < 2; ++c)
            bfrag[nt][c] = *(const bf16x8*)(wt +
                ((size_t)(col0 + nt * 16 + l16) * 64 + c * 32 + quad * 8));

    f32x4 acc[MT][NT];
#pragma unroll
    for (int mt = 0; mt < MT; ++mt)
#pragma unroll
        for (int nt = 0; nt < NT; ++nt)
            acc[mt][nt] = f32x4{0.f, 0.f, 0.f, 0.f};

#pragma unroll
    for (int mt = 0; mt < MT; ++mt) {
        int row = row0 + mt * 16 + l16;
        row = (row < NNODES) ? row : (NNODES - 1);
#pragma unroll
        for (int c = 0; c < 2; ++c) {
            bf16x8 afrag = *(const bf16x8*)(xc + ((size_t)row * 64 + c * 32 + quad * 8));
#pragma unroll
            for (int nt = 0; nt < NT; ++nt)
                acc[mt][nt] = __builtin_amdgcn_mfma_f32_16x16x32_bf16(
                    afrag, bfrag[nt][c], acc[mt][nt], 0, 0, 0);
        }
    }

#pragma unroll
    for (int mt = 0; mt < MT; ++mt) {
#pragma unroll
        for (int nt = 0; nt < NT; ++nt) {
            const int col = col0 + nt * 16 + l16;
            const float bias = u2f(bc[col]);
#pragma unroll
            for (int r = 0; r < 4; ++r) {
                const int row = row0 + mt * 16 + quad * 4 + r;
                if (row < NNODES)
                    out[(size_t)row * M + col] = f2u(acc[mt][nt][r] + bias);
            }
        }
    }
}

// ------- layer-1 fused GAT: 4 edges/wave-iter, depth-2 prefetch ------------
__global__ __launch_bounds__(256)
void gat_l1(const u16* __restrict__ xl, const u16* __restrict__ xr,
            const int* __restrict__ row_ptr, const int* __restrict__ csr_src,
            const void* __restrict__ att, const void* __restrict__ bo,
            const int* __restrict__ flags, u16* __restrict__ out) {
    const int d = blockIdx.x * 4 + (threadIdx.x >> 6);
    if (d >= NNODES) return;
    const int lane = threadIdx.x & 63;
    const int q = lane >> 4;
    const int l = lane & 15;
    const int fatt = flags[F_ATT1];

    float attv[4], rv[4];
#pragma unroll
    for (int j = 0; j < 4; ++j)
        attv[j] = ld_any(att, l * 4 + j, fatt);
    {
        ushort4 r = *(const ushort4*)(xr + (size_t)d * 64 + l * 4);
        rv[0]=u2f(r.x); rv[1]=u2f(r.y); rv[2]=u2f(r.z); rv[3]=u2f(r.w);
    }

    const int beg = row_ptr[d], end = row_ptr[d + 1];
    float denom = 1e-16f;
    float acc[4] = {0.f, 0.f, 0.f, 0.f};

    ushort4 aA, aB;
    {
        int ia = beg + q;     ia = (ia < end) ? ia : (end - 1);
        aA = *(const ushort4*)(xl + (size_t)csr_src[ia] * 64 + l * 4);
        int ib = beg + 4 + q; ib = (ib < end) ? ib : (end - 1);
        aB = *(const ushort4*)(xl + (size_t)csr_src[ib] * 64 + l * 4);
    }

    for (int base = beg; base < end; base += 8) {
        {   // group A: edges base+q
            float lv[4];
            lv[0]=u2f(aA.x); lv[1]=u2f(aA.y); lv[2]=u2f(aA.z); lv[3]=u2f(aA.w);
            if (base + 8 < end) {
                int ia = base + 8 + q; ia = (ia < end) ? ia : (end - 1);
                aA = *(const ushort4*)(xl + (size_t)csr_src[ia] * 64 + l * 4);
            }
            float part = 0.f;
#pragma unroll
            for (int j = 0; j < 4; ++j) {
                float v = lv[j] + rv[j];
                v = fmaxf(v, 0.2f * v);
                part = fmaf(v, attv[j], part);
            }
            part += __shfl_xor(part, 1, 64);
            part += __shfl_xor(part, 2, 64);
            float ex = __expf(fminf(part, 60.f));
            ex = (base + q < end) ? ex : 0.f;
            denom += ex;
#pragma unroll
            for (int j = 0; j < 4; ++j)
                acc[j] = fmaf(ex, lv[j], acc[j]);
        }
        if (base + 4 < end) {   // group B: edges base+4+q
            float lv[4];
            lv[0]=u2f(aB.x); lv[1]=u2f(aB.y); lv[2]=u2f(aB.z); lv[3]=u2f(aB.w);
            if (base + 12 < end) {
                int ib = base + 12 + q; ib = (ib < end) ? ib : (end - 1);
                aB = *(const ushort4*)(xl + (size_t)csr_src[ib] * 64 + l * 4);
            }
            float part = 0.f;
#pragma unroll
            for (int j = 0; j < 4; ++j) {
                float v = lv[j] + rv[j];
                v = fmaxf(v, 0.2f * v);
                part = fmaf(v, attv[j], part);
            }
            part += __shfl_xor(part, 1, 64);
            part += __shfl_xor(part, 2, 64);
            float ex = __expf(fminf(part, 60.f));
            ex = (base + 4 + q < end) ? ex : 0.f;
            denom += ex;
#pragma unroll
            for (int j = 0; j < 4; ++j)
                acc[j] = fmaf(ex, lv[j], acc[j]);
        }
    }

    denom += __shfl_xor(denom, 16, 64);          // combine the 4 edge slots
    denom += __shfl_xor(denom, 32, 64);
#pragma unroll
    for (int j = 0; j < 4; ++j) {
        acc[j] += __shfl_xor(acc[j], 16, 64);
        acc[j] += __shfl_xor(acc[j], 32, 64);
    }
    const float inv = 1.f / denom;

    if (lane < 16) {                             // lanes 0-15: channels 4l..4l+3
        const int fbo = flags[F_BO1];
        ushort4 o;
        u16* op = (u16*)&o;
#pragma unroll
        for (int j = 0; j < 4; ++j) {
            float v = acc[j] * inv + ld_any(bo, l * 4 + j, fbo);
            op[j] = f2u((v > 0.f) ? v : 0.f);
        }
        *(ushort4*)(out + (size_t)d * 64 + l * 4) = o;
    }
}

// ------- layer-2 fused GAT: 2 edges/wave, 32 lanes/edge, depth-2 prefetch --
__global__ __launch_bounds__(256)
void gat_l2(const u16* __restrict__ xl, const u16* __restrict__ xr,
            const int* __restrict__ row_ptr, const int* __restrict__ csr_src,
            const void* __restrict__ att, const void* __restrict__ bo,
            const int* __restrict__ flags, float* __restrict__ out) {
    const int d = blockIdx.x * 4 + (threadIdx.x >> 6);
    if (d >= NNODES) return;
    const int lane = threadIdx.x & 63;
    const int half = lane >> 5;
    const int l    = lane & 31;          // channels 8l..8l+7
    const int fatt = flags[F_ATT2];

    v2f attv[4], rv[4];
#pragma unroll
    for (int j = 0; j < 4; ++j) {
        v2f a;
        a.x = ld_any(att, l * 8 + 2 * j,     fatt);
        a.y = ld_any(att, l * 8 + 2 * j + 1, fatt);
        attv[j] = a;
    }
    {
        uint4 r = *(const uint4*)(xr + (size_t)d * 256 + l * 8);
        rv[0] = cvt2(r.x); rv[1] = cvt2(r.y); rv[2] = cvt2(r.z); rv[3] = cvt2(r.w);
    }

    const int beg = row_ptr[d], end = row_ptr[d + 1];   // end > beg (self loop)
    float denom = 1e-16f;
    v2f acc[4];
#pragma unroll
    for (int j = 0; j < 4; ++j) acc[j] = (v2f){0.f, 0.f};

    uint4 rawA, rawB;
    {
        int ia = beg + half;     ia = (ia < end) ? ia : (end - 1);
        rawA = *(const uint4*)(xl + (size_t)csr_src[ia] * 256 + l * 8);
        int ib = beg + 2 + half; ib = (ib < end) ? ib : (end - 1);
        rawB = *(const uint4*)(xl + (size_t)csr_src[ib] * 256 + l * 8);
    }

    for (int base = beg; base < end; base += 4) {
        {   // pair A: edges base+half
            v2f lv[4];
            lv[0] = cvt2(rawA.x); lv[1] = cvt2(rawA.y);
            lv[2] = cvt2(rawA.z); lv[3] = cvt2(rawA.w);
            if (base + 4 < end) {
                int ia = base + 4 + half; ia = (ia < end) ? ia : (end - 1);
                rawA = *(const uint4*)(xl + (size_t)csr_src[ia] * 256 + l * 8);
            }
            v2f p = (v2f){0.f, 0.f};
#pragma unroll
            for (int j = 0; j < 4; ++j) {
                v2f v = lv[j] + rv[j];
                v2f t = v * 0.2f;
                v.x = fmaxf(v.x, t.x);
                v.y = fmaxf(v.y, t.y);
                p += v * attv[j];
            }
            float part = p.x + p.y;
            part += __shfl_xor(part, 1, 64);
            part += __shfl_xor(part, 2, 64);
            part += __shfl_xor(part, 4, 64);
            float ex = __expf(fminf(part, 60.f));
            ex = (base + half < end) ? ex : 0.f;
            denom += ex;
#pragma unroll
            for (int j = 0; j < 4; ++j)
                acc[j] += lv[j] * ex;
        }
        if (base + 2 < end) {   // pair B: edges base+2+half
            v2f lv[4];
            lv[0] = cvt2(rawB.x); lv[1] = cvt2(rawB.y);
            lv[2] = cvt2(rawB.z); lv[3] = cvt2(rawB.w);
            if (base + 6 < end) {
                int ib = base + 6 + half; ib = (ib < end) ? ib : (end - 1);
                rawB = *(const uint4*)(xl + (size_t)csr_src[ib] * 256 + l * 8);
            }
            v2f p = (v2f){0.f, 0.f};
#pragma unroll
            for (int j = 0; j < 4; ++j) {
                v2f v = lv[j] + rv[j];
                v2f t = v * 0.2f;
                v.x = fmaxf(v.x, t.x);
                v.y = fmaxf(v.y, t.y);
                p += v * attv[j];
            }
            float part = p.x + p.y;
            part += __shfl_xor(part, 1, 64);
            part += __shfl_xor(part, 2, 64);
            part += __shfl_xor(part, 4, 64);
            float ex = __expf(fminf(part, 60.f));
            ex = (base + 2 + half < end) ? ex : 0.f;
            denom += ex;
#pragma unroll
            for (int j = 0; j < 4; ++j)
                acc[j] += lv[j] * ex;
        }
    }

    // combine the two edge halves (lanes l and l+32 share channels)
    denom += __shfl_xor(denom, 32, 64);
#pragma unroll
    for (int j = 0; j < 4; ++j) {
        acc[j].x += __shfl_xor(acc[j].x, 32, 64);
        acc[j].y += __shfl_xor(acc[j].y, 32, 64);
    }
    const float inv = 1.f / denom;               // this head's denom
#pragma unroll
    for (int j = 0; j < 4; ++j) {
        acc[j] *= inv;
        acc[j].x += __shfl_xor(acc[j].x, 8, 64); // sum the 4 heads
        acc[j].y += __shfl_xor(acc[j].y, 8, 64);
        acc[j].x += __shfl_xor(acc[j].x, 16, 64);
        acc[j].y += __shfl_xor(acc[j].y, 16, 64);
    }
    if (lane < 8) {                              // lanes 0-7: channels 8l..8l+7
        const int fbo = flags[F_BO2];
        float vv[8];
#pragma unroll
        for (int j = 0; j < 4; ++j) { vv[2*j] = acc[j].x; vv[2*j+1] = acc[j].y; }
#pragma unroll
        for (int k = 0; k < 8; ++k) {
            float v = vv[k] * 0.25f + ld_any(bo, l * 8 + k, fbo);
            vv[k] = (v > 0.f) ? v : 0.f;
        }
        float* po = out + (size_t)d * 64 + l * 8;
        *(float4*)po       = make_float4(vv[0], vv[1], vv[2], vv[3]);
        *(float4*)(po + 4) = make_float4(vv[4], vv[5], vv[6], vv[7]);
    }
}

__global__ void plant_kernel(float* out, float code) {
    if (code > 0.f) out[0] = code;
}

extern "C" void kernel_launch(void* const* d_in, const int* in_sizes, int n_in,
                              void* d_out, int out_size, void* d_ws, size_t ws_size,
                              hipStream_t stream) {
    // ---- host-side slot mapping by element counts ----
    int ix = -1, iei = -1;
    int i4096[2], i16384[2], i64s[5], i256[3];
    int c4 = 0, c16 = 0, c64 = 0, c256 = 0;
    bool extra = false;
    for (int i = 0; i < n_in; ++i) {
        int sz = in_sizes[i];
        if (sz == 6400000)      { if (ix < 0) ix = i; else extra = true; }
        else if (sz == 3200000) { if (iei < 0) iei = i; else extra = true; }
        else if (sz == 4096)    { if (c4  < 2) i4096[c4]  = i; c4++;  }
        else if (sz == 16384)   { if (c16 < 2) i16384[c16] = i; c16++; }
        else if (sz == 64)      { if (c64 < 5) i64s[c64]  = i; c64++; }
        else if (sz == 256)     { if (c256 < 3) i256[c256] = i; c256++; }
        else if (sz == 100000 || sz == 1) { /* frame_mask / scalar: unused */ }
        else extra = true;
    }
    bool ok = (ix >= 0) && (iei >= 0) && (c4 == 2) && (c16 == 2)
              && (c64 == 5) && (c256 == 3) && !extra;
    float code = 0.f;
    if (!ok) {
        code = 50000.f + 100.f * (float)n_in;
        ix = 0; iei = 1;
        i4096[0] = 3;  i4096[1] = 5;
        i64s[0] = 4; i64s[1] = 6; i64s[2] = 7; i64s[3] = 8; i64s[4] = 14;
        i16384[0] = 9; i16384[1] = 11;
        i256[0] = 10; i256[1] = 12; i256[2] = 13;
    }

    const u16* x    = (const u16*)d_in[ix];
    const int* ei   = (const int*)d_in[iei];
    const u16* Wl1  = (const u16*)d_in[i4096[0]];
    const u16* Wr1  = (const u16*)d_in[i4096[1]];
    const u16* bl1  = (const u16*)d_in[i64s[0]];
    const u16* br1  = (const u16*)d_in[i64s[1]];
    const u16* att1 = (const u16*)d_in[i64s[2]];
    const u16* bo1  = (const u16*)d_in[i64s[3]];
    const u16* bo2  = (const u16*)d_in[i64s[4]];
    const u16* Wl2  = (const u16*)d_in[i16384[0]];
    const u16* Wr2  = (const u16*)d_in[i16384[1]];
    const u16* bl2  = (const u16*)d_in[i256[0]];
    const u16* br2  = (const u16*)d_in[i256[1]];
    const u16* att2 = (const u16*)d_in[i256[2]];

    // ---- workspace layout (bytes), ~136.1 MB ----
    char* ws = (char*)d_ws;
    u16* xlb     = (u16*)(ws);                    // N*256 bf16 = 51.2 MB
    u16* xrb     = (u16*)(ws + 51200000);         // N*256 bf16 = 51.2 MB
    u16* hbuf    = (u16*)(ws + 102400000);        // N*64  bf16 = 12.8 MB
    u16* xc      = (u16*)(ws + 115200000);        // N*64  bf16 = 12.8 MB
    int* row_ptr = (int*)(ws + 128000000);        // (N+1)*4
    int* cnt     = (int*)(ws + 128400016);        // N*4
    int* tmp     = (int*)(ws + 128800016);        // N*4
    int* bsum    = (int*)(ws + 129200016);        // NB*4
    int* csr_src = (int*)(ws + 129201600);        // EPLUS*4 = 6.8 MB
    u16* wt1l    = (u16*)(ws + 136001600);        // 64*64 bf16
    u16* wt1r    = (u16*)(ws + 136009792);
    u16* wt2l    = (u16*)(ws + 136017984);        // 256*64 bf16
    u16* wt2r    = (u16*)(ws + 136050752);
    u16* bcs     = (u16*)(ws + 136083520);        // 640 bf16
    int* flags   = (int*)(ws + 136084800);        // 16 ints
    const size_t need = 136084864;
    if (ws_size < need) {
        float c2 = 60000.f + (float)(ws_size >> 20);
        code = (c2 > code) ? c2 : code;
    }

    const int node_grid = (NNODES + 3) / 4;       // 25000
    const int ep_grid   = (EPLUS + 255) / 256;

    detect_all<<<14, 64, 0, stream>>>(x, Wl1, bl1, Wr1, br1, att1, bo1,
                                      Wl2, bl2, Wr2, br2, att2, bo2, ei, flags);

    // ---- canonicalize + histogram (one dispatch) ----
    (void)hipMemsetAsync(cnt, 0, (size_t)NNODES * 4, stream);
    conv_all<<<XB + WB + BB + HB, 256, 0, stream>>>(
        x, Wl1, Wr1, Wl2, Wr2, bl1, br1, bl2, br2, ei, flags,
        xc, wt1l, wt1r, wt2l, wt2r, bcs, cnt);

    // ---- CSR scan + fill ----
    scan1_kernel<<<NB, 256, 0, stream>>>(cnt, tmp, bsum);
    scan2_kernel<<<1, 512, 0, stream>>>(bsum);
    scan3_kernel<<<NB, 256, 0, stream>>>(tmp, bsum, row_ptr);
    (void)hipMemsetAsync(cnt, 0, (size_t)NNODES * 4, stream);
    fill_kernel<<<ep_grid, 256, 0, stream>>>(ei, flags, row_ptr, cnt, csr_src);

    // ---- layer 1 (64 -> 4x16, concat) ----
    gemm_mfma<64, 128><<<dim3((NNODES + 127) / 128, 2), 256, 0, stream>>>(
        xc, wt1l, wt1r, bcs, bcs + 64, xlb, xrb);
    gat_l1<<<node_grid, 256, 0, stream>>>(
        xlb, xrb, row_ptr, csr_src, att1, bo1, flags, hbuf);

    // ---- layer 2 (64 -> 4x64, mean) ----
    gemm_mfma<256, 64><<<dim3((NNODES + 63) / 64, 2), 256, 0, stream>>>(
        hbuf, wt2l, wt2r, bcs + 128, bcs + 384, xlb, xrb);
    gat_l2<<<node_grid, 256, 0, stream>>>(
        xlb, xrb, row_ptr, csr_src, att2, bo2, flags, (float*)d_out);

    plant_kernel<<<1, 1, 0, stream>>>((float*)d_out, code);
}